// Round 19
// baseline (316.414 us; speedup 1.0000x reference)
//
#include <hip/hip_runtime.h>
#include <math.h>

#define S 128
#define R 256
#define DMODEL 256
#define H 8
#define CDIM 32
#define HC 256
#define DFF 1024
#define NROWS (S*R)     // 32768
#define NPAIR (R*R)     // 65536
#define LN_EPS 1e-5f
#define LOG2E 1.4426950408889634f
#define M32 ((size_t)NROWS * 32)

typedef unsigned short u16;
typedef __attribute__((ext_vector_type(8))) short bf16x8;
typedef __attribute__((ext_vector_type(4))) float f32x4;
typedef __attribute__((ext_vector_type(16))) float f32x16;

__device__ __forceinline__ u16 f2bf(float x) {
  unsigned u = __float_as_uint(x);
  u = (u + 0x7fffu + ((u >> 16) & 1u)) >> 16;
  return (u16)u;
}
__device__ __forceinline__ float bf2f(u16 x) {
  return __uint_as_float(((unsigned)x) << 16);
}
__device__ __forceinline__ unsigned cvt_pk(float a, float b) {
  unsigned r;
  asm("v_cvt_pk_bf16_f32 %0, %1, %2" : "=v"(r) : "v"(a), "v"(b));
  return r;
}
__device__ __forceinline__ void pl32swap(unsigned &a, unsigned &b) {
  asm("v_permlane32_swap_b32 %0, %1" : "+v"(a), "+v"(b));
}
__device__ __forceinline__ bf16x8 mk_frag(unsigned a, unsigned b, unsigned c, unsigned d) {
  uint4 t = make_uint4(a, b, c, d);
  return __builtin_bit_cast(bf16x8, t);
}

__device__ __forceinline__ void gload_lds16(const u16* g, u16* l) {
  __builtin_amdgcn_global_load_lds(
      (const __attribute__((address_space(1))) unsigned int*)g,
      (__attribute__((address_space(3))) unsigned int*)l, 16, 0, 0);
}

// ---------------- weight f32 -> bf16 conversion (12 segments) ----------------
struct CvtArgs {
  const float* src[12];
  int off[12];
  int n[12];
  float scale[12];
};

__global__ __launch_bounds__(256) void cvt_w_kernel(CvtArgs a, u16* __restrict__ dst) {
  int sg = blockIdx.y;
  int i = (blockIdx.x * 256 + threadIdx.x) * 4;
  if (i >= a.n[sg]) return;
  float4 v = *(const float4*)(a.src[sg] + i);
  float sc = a.scale[sg];
  uint2 o;
  o.x = cvt_pk(v.x * sc, v.y * sc);
  o.y = cvt_pk(v.z * sc, v.w * sc);
  *(uint2*)(dst + a.off[sg] + i) = o;
}

// ---------------- LayerNorm over 256, one row per wave, bf16 out ----------------
__global__ __launch_bounds__(256) void ln256_kernel(
    const void* __restrict__ in, u16* __restrict__ out,
    const float* __restrict__ gamma, const float* __restrict__ beta,
    int tmode, int inbf)
{
  int wid = threadIdx.x >> 6, lane = threadIdx.x & 63;
  int m = blockIdx.x * 4 + wid;
  int inrow = m;
  if (tmode) { int r = m >> 7, s = m & 127; inrow = s * R + r; }
  float4 x;
  if (inbf) {
    ushort4 u = *(const ushort4*)((const u16*)in + (size_t)inrow * DMODEL + lane * 4);
    x.x = bf2f(u.x); x.y = bf2f(u.y); x.z = bf2f(u.z); x.w = bf2f(u.w);
  } else {
    x = *(const float4*)((const float*)in + (size_t)inrow * DMODEL + lane * 4);
  }
  float sum = x.x + x.y + x.z + x.w;
  float sq  = x.x*x.x + x.y*x.y + x.z*x.z + x.w*x.w;
  #pragma unroll
  for (int off = 32; off; off >>= 1) {
    sum += __shfl_xor(sum, off);
    sq  += __shfl_xor(sq, off);
  }
  float mean = sum * (1.0f/256.0f);
  float var  = sq  * (1.0f/256.0f) - mean*mean;
  float rstd = rsqrtf(var + LN_EPS);
  float4 g = *(const float4*)(gamma + lane*4);
  float4 b = *(const float4*)(beta  + lane*4);
  uint2 o;
  o.x = cvt_pk((x.x-mean)*rstd*g.x + b.x, (x.y-mean)*rstd*g.y + b.y);
  o.y = cvt_pk((x.z-mean)*rstd*g.z + b.z, (x.w-mean)*rstd*g.w + b.w);
  *(uint2*)(out + (size_t)m * DMODEL + lane*4) = o;
}

// -- pair LN (over 128) + bias projection -> FRAGMENT layout bias (bf16, *log2e) --
// 16 lanes per row, 4 rows per wave, 16 rows per block.
__global__ __launch_bounds__(256) void pair_bias_kernel(
    const float* __restrict__ pair, const float* __restrict__ gamma,
    const float* __restrict__ beta, const float* __restrict__ bw,
    u16* __restrict__ bias)
{
  int t = threadIdx.x;
  int lane = t & 63, wv = t >> 6;
  int sub = lane >> 4, l16 = lane & 15;
  int p = blockIdx.x * 16 + wv * 4 + sub;    // row index = q*256 + k
  const float* xp = pair + (size_t)p * 128 + l16 * 8;
  float4 x0 = *(const float4*)xp;
  float4 x1 = *(const float4*)(xp + 4);
  float xs[8] = {x0.x, x0.y, x0.z, x0.w, x1.x, x1.y, x1.z, x1.w};

  float sum = 0.f, sq = 0.f;
  #pragma unroll
  for (int j = 0; j < 8; ++j) { sum += xs[j]; sq += xs[j]*xs[j]; }
  #pragma unroll
  for (int d = 1; d < 16; d <<= 1) {
    sum += __shfl_xor(sum, d);
    sq  += __shfl_xor(sq, d);
  }
  float mean = sum * (1.0f/128.0f);
  float rstd = rsqrtf(sq*(1.0f/128.0f) - mean*mean + LN_EPS);

  const float* gp = gamma + l16*8;
  const float* bp = beta  + l16*8;
  float4 g0 = *(const float4*)gp, g1 = *(const float4*)(gp + 4);
  float4 b0 = *(const float4*)bp, b1 = *(const float4*)(bp + 4);
  float gg[8] = {g0.x,g0.y,g0.z,g0.w,g1.x,g1.y,g1.z,g1.w};
  float bb[8] = {b0.x,b0.y,b0.z,b0.w,b1.x,b1.y,b1.z,b1.w};
  float z[8];
  #pragma unroll
  for (int j = 0; j < 8; ++j) z[j] = (xs[j]-mean)*rstd*gg[j] + bb[j];

  float a[8];
  #pragma unroll
  for (int h = 0; h < 8; ++h) {
    const float* wp = bw + h*128 + l16*8;
    float4 w0 = *(const float4*)wp, w1 = *(const float4*)(wp + 4);
    a[h] = z[0]*w0.x + z[1]*w0.y + z[2]*w0.z + z[3]*w0.w
         + z[4]*w1.x + z[5]*w1.y + z[6]*w1.z + z[7]*w1.w;
  }

  #pragma unroll
  for (int i = 0; i < 4; ++i) {
    float send = (lane & 1) ? a[i] : a[i+4];
    float recv = __shfl_xor(send, 1);
    a[i] = ((lane & 1) ? a[i+4] : a[i]) + recv;
  }
  #pragma unroll
  for (int i = 0; i < 2; ++i) {
    float send = (lane & 2) ? a[i] : a[i+2];
    float recv = __shfl_xor(send, 2);
    a[i] = ((lane & 2) ? a[i+2] : a[i]) + recv;
  }
  {
    float send = (lane & 4) ? a[0] : a[1];
    float recv = __shfl_xor(send, 4);
    a[0] = ((lane & 4) ? a[1] : a[0]) + recv;
  }
  a[0] += __shfl_xor(a[0], 8);
  int h = 4*(l16 & 1) + (l16 & 2) + ((l16 >> 2) & 1);

  if (l16 < 8) {
    int q = p >> 8, k = p & 255;
    int kt = k >> 5, qt = q >> 5, c31 = q & 31;
    int kk = k & 31;
    int hi2 = (kk >> 2) & 1;
    int j = (kk & 3) | ((kk >> 3) << 2);
    size_t addr = ((((size_t)h*8 + kt)*8 + qt)*2 + hi2)*512 + (size_t)c31*16 + j;
    bias[addr] = f2bf(a[0] * LOG2E);
  }
}

// ---------- shared epilogue for one (row, col0, f32x4) output quad ----------
__device__ __forceinline__ void epi_store(
    int mode, void* __restrict__ Cout, int N,
    const float* __restrict__ bias, const float* __restrict__ res,
    int row, int col0, f32x4 v)
{
  const u16* resb = (const u16*)res;
  if (mode == 6) {
    if (col0 >= 768) {
      float4 b4 = *(const float4*)(bias + col0 - 768);
      v[0] = 1.0f/(1.0f+__expf(-(v[0]+b4.x)));
      v[1] = 1.0f/(1.0f+__expf(-(v[1]+b4.y)));
      v[2] = 1.0f/(1.0f+__expf(-(v[2]+b4.z)));
      v[3] = 1.0f/(1.0f+__expf(-(v[3]+b4.w)));
    }
    uint2 o; o.x = cvt_pk(v[0], v[1]); o.y = cvt_pk(v[2], v[3]);
    size_t i2 = (size_t)(col0 >> 5) * M32 + (size_t)row*32 + (col0 & 31);
    *(uint2*)((u16*)Cout + i2) = o;
  } else if (mode == 3) {
    float4 b4 = *(const float4*)(bias + col0);
    uint2 o;
    o.x = cvt_pk(fmaxf(v[0]+b4.x, 0.f), fmaxf(v[1]+b4.y, 0.f));
    o.y = cvt_pk(fmaxf(v[2]+b4.z, 0.f), fmaxf(v[3]+b4.w, 0.f));
    *(uint2*)((u16*)Cout + (size_t)row*N + col0) = o;
  } else if (mode == 7) {
    size_t i2 = (size_t)row*N + col0;
    float4 r4 = *(const float4*)(res + i2);
    float4 b4 = *(const float4*)(bias + col0);
    uint2 o;
    o.x = cvt_pk(v[0]+r4.x+b4.x, v[1]+r4.y+b4.y);
    o.y = cvt_pk(v[2]+r4.z+b4.z, v[3]+r4.w+b4.w);
    *(uint2*)((u16*)Cout + i2) = o;
  } else if (mode == 8) {
    int rr = row >> 7, ss = row & 127;
    size_t i2 = ((size_t)ss*R + rr)*(size_t)N + col0;
    ushort4 r4 = *(const ushort4*)(resb + i2);
    float4 b4 = *(const float4*)(bias + col0);
    uint2 o;
    o.x = cvt_pk(v[0]+bf2f(r4.x)+b4.x, v[1]+bf2f(r4.y)+b4.y);
    o.y = cvt_pk(v[2]+bf2f(r4.z)+b4.z, v[3]+bf2f(r4.w)+b4.w);
    *(uint2*)((u16*)Cout + i2) = o;
  } else if (mode == 9) {
    size_t i2 = (size_t)row*N + col0;
    ushort4 r4 = *(const ushort4*)(resb + i2);
    float4 b4 = *(const float4*)(bias + col0);
    float4 o = make_float4(v[0]+bf2f(r4.x)+b4.x, v[1]+bf2f(r4.y)+b4.y,
                           v[2]+bf2f(r4.z)+b4.z, v[3]+bf2f(r4.w)+b4.w);
    *(float4*)((float*)Cout + i2) = o;
  } else {
    uint2 o; o.x = cvt_pk(v[0], v[1]); o.y = cvt_pk(v[2], v[3]);
    *(uint2*)((u16*)Cout + (size_t)row*N + col0) = o;
  }
}

// ---------------- bf16 MFMA NT GEMM v2: 128x128 tile, 256 thr / 4 waves, BK=32 ----
__global__ __launch_bounds__(256, 4) void gemm_v2(
    const u16* __restrict__ A, const u16* __restrict__ W,
    void* __restrict__ Cout, int N, int K,
    int mode, const float* __restrict__ bias, const float* __restrict__ res)
{
  __shared__ u16 lds[2][2][128*32];
  int t = threadIdx.x, lane = t & 63, wv = t >> 6;
  int g16 = (lane >> 4) & 3, l16 = lane & 15;
  int wm = wv >> 1, wn = wv & 1;

  int gx = gridDim.x;
  int nwg = gx * gridDim.y;
  int p = blockIdx.y * gx + blockIdx.x;
  int cpx = nwg >> 3;
  int lg = (p & 7) * cpx + (p >> 3);
  int bn = (lg % gx) * 128;
  int bm = (lg / gx) * 128;

  int sr = t >> 2;
  int swz8 = ((t & 3) ^ ((sr >> 1) & 3)) << 3;
  int rdch = (g16 ^ ((l16 >> 1) & 3)) << 3;
  int rdoff = l16 * 32 + rdch;

  f32x4 acc[4][4];
  #pragma unroll
  for (int i = 0; i < 4; ++i)
    #pragma unroll
    for (int j = 0; j < 4; ++j) acc[i][j] = (f32x4){0.f,0.f,0.f,0.f};

  const int nkt = K >> 5;

#define STAGE(buf_, kc_) do { \
    gload_lds16(A + (size_t)(bm + sr) * K + (kc_) + swz8, &lds[buf_][0][t*8]); \
    gload_lds16(A + (size_t)(bm + 64 + sr) * K + (kc_) + swz8, &lds[buf_][0][2048 + t*8]); \
    gload_lds16(W + (size_t)(bn + sr) * K + (kc_) + swz8, &lds[buf_][1][t*8]); \
    gload_lds16(W + (size_t)(bn + 64 + sr) * K + (kc_) + swz8, &lds[buf_][1][2048 + t*8]); \
  } while(0)

  STAGE(0, 0);
  for (int kt = 0; kt < nkt; ++kt) {
    if (kt + 1 < nkt) {
      STAGE((kt + 1) & 1, (kt + 1) * 32);
      asm volatile("s_waitcnt vmcnt(4)" ::: "memory");
    } else {
      asm volatile("s_waitcnt vmcnt(0)" ::: "memory");
    }
    __builtin_amdgcn_s_barrier();
    int buf = kt & 1;
    const u16* Abase = &lds[buf][0][wm*2048];
    const u16* Wbase = &lds[buf][1][wn*2048];
    bf16x8 wf[4];
    #pragma unroll
    for (int nf = 0; nf < 4; ++nf)
      wf[nf] = *(const bf16x8*)(Wbase + nf*512 + rdoff);
    __builtin_amdgcn_s_setprio(1);
    #pragma unroll
    for (int mf = 0; mf < 4; ++mf) {
      bf16x8 a0 = *(const bf16x8*)(Abase + mf*512 + rdoff);
      #pragma unroll
      for (int nf = 0; nf < 4; ++nf)
        acc[mf][nf] = __builtin_amdgcn_mfma_f32_16x16x32_bf16(wf[nf], a0, acc[mf][nf], 0, 0, 0);
    }
    __builtin_amdgcn_s_setprio(0);
    asm volatile("" ::: "memory");
    __builtin_amdgcn_s_barrier();
  }
#undef STAGE

  int rowb = bm + wm*64 + l16;
  int colb = bn + wn*64 + (g16 << 2);
  #pragma unroll
  for (int mf = 0; mf < 4; ++mf) {
    int row = rowb + mf*16;
    #pragma unroll
    for (int nf = 0; nf < 4; ++nf)
      epi_store(mode, Cout, N, bias, res, row, colb + nf*16, acc[mf][nf]);
  }
}

// ---- softmax + pack: bias comes pre-packed in fragment order (2x bf16x8) ----
template<bool RM>
__device__ __forceinline__ void softmax_pack(
    const f32x16 &sac, const float* __restrict__ lmbp,
    bf16x8 bf0, bf16x8 bf1, int kb, int hi,
    float &lsum, bf16x8 &pf0, bf16x8 &pf1)
{
  float p[16];
  #pragma unroll
  for (int rq = 0; rq < 4; ++rq) {
    int k0 = kb + 8*rq + 4*hi;
    float4 lm4 = *(const float4*)&lmbp[k0];
    float b0 = lm4.x, b1 = lm4.y, b2 = lm4.z, b3 = lm4.w;
    if (RM) {
      if (rq < 2) {
        b0 += bf2f((u16)bf0[4*rq+0]); b1 += bf2f((u16)bf0[4*rq+1]);
        b2 += bf2f((u16)bf0[4*rq+2]); b3 += bf2f((u16)bf0[4*rq+3]);
      } else {
        b0 += bf2f((u16)bf1[4*rq-8+0]); b1 += bf2f((u16)bf1[4*rq-8+1]);
        b2 += bf2f((u16)bf1[4*rq-8+2]); b3 += bf2f((u16)bf1[4*rq-8+3]);
      }
    }
    p[4*rq+0] = exp2f(sac[4*rq+0] + b0);
    p[4*rq+1] = exp2f(sac[4*rq+1] + b1);
    p[4*rq+2] = exp2f(sac[4*rq+2] + b2);
    p[4*rq+3] = exp2f(sac[4*rq+3] + b3);
    lsum += (p[4*rq+0] + p[4*rq+1]) + (p[4*rq+2] + p[4*rq+3]);
  }
  unsigned u0 = cvt_pk(p[0],  p[1]),  u1 = cvt_pk(p[2],  p[3]);
  unsigned u2 = cvt_pk(p[4],  p[5]),  u3 = cvt_pk(p[6],  p[7]);
  unsigned u4 = cvt_pk(p[8],  p[9]),  u5 = cvt_pk(p[10], p[11]);
  unsigned u6 = cvt_pk(p[12], p[13]), u7 = cvt_pk(p[14], p[15]);
  pl32swap(u0, u2); pl32swap(u1, u3);
  pl32swap(u4, u6); pl32swap(u5, u7);
  pf0 = mk_frag(u0, u1, u2, u3);
  pf1 = mk_frag(u4, u5, u6, u7);
}

// ---------------- MFMA attention, 32x32, 256 thr / 4 waves, head-major QKVG ----
// HPB heads per block; WPH = 4/HPB waves per head; each wave owns 2 q-tiles (64 q).
// row: HPB=1, grid (8,128); col: HPB=2, grid (4,256) -> 1024 blocks, 4+ blocks/CU.
template<int NKEY, int HPB, bool ROWMODE>
__global__ __launch_bounds__(256, 4) void attn_mfma(
    const u16* __restrict__ QKVG, const u16* __restrict__ biasF,
    const float* __restrict__ mask, u16* __restrict__ og)
{
  __shared__ __align__(16) u16 Vt[HPB][32][NKEY + 8];
  __shared__ float lmb[NKEY];
  constexpr int NKV = NKEY / 32;
  constexpr int WPH = 4 / HPB;
  int b = blockIdx.y;
  int t = threadIdx.x, lane = t & 63, w = t >> 6;
  int c31 = lane & 31, hi = lane >> 5;
  int lh = w / WPH, wtile = w % WPH;
  int hh = blockIdx.x * HPB + lh;

  size_t rbase = (size_t)b * NKEY * 32;
  const u16* Qp = QKVG + (size_t)hh * M32 + rbase;
  const u16* Kp = QKVG + (size_t)(8 + hh) * M32 + rbase;
  const u16* Gp = QKVG + (size_t)(24 + hh) * M32 + rbase;

  for (int i = t; i < HPB*NKEY*4; i += 256) {
    int c0 = (i & 3) * 8;
    int key = (i >> 2) & (NKEY - 1);
    int sh = (i >> 2) / NKEY;
    const u16* Vs = QKVG + (size_t)(16 + blockIdx.x*HPB + sh) * M32 + rbase;
    bf16x8 v8 = *(const bf16x8*)(Vs + (size_t)key*32 + c0);
    #pragma unroll
    for (int j = 0; j < 8; ++j) Vt[sh][c0+j][key] = (u16)v8[j];
  }
  for (int i = t; i < NKEY; i += 256)
    lmb[i] = 1.4426950e9f * ((ROWMODE ? mask[b*R + i] : mask[i*R + b]) - 1.0f);
  __syncthreads();

  int qA = wtile*64 + c31, qB = qA + 32;
  int qtA = wtile*2, qtB = wtile*2 + 1;
  bf16x8 qfA0 = *(const bf16x8*)(Qp + (size_t)qA*32 + hi*8);
  bf16x8 qfA1 = *(const bf16x8*)(Qp + (size_t)qA*32 + 16 + hi*8);
  bf16x8 qfB0 = *(const bf16x8*)(Qp + (size_t)qB*32 + hi*8);
  bf16x8 qfB1 = *(const bf16x8*)(Qp + (size_t)qB*32 + 16 + hi*8);

  f32x16 oA = (f32x16)(0.0f), oB = (f32x16)(0.0f);
  float lsA = 0.f, lsB = 0.f;

#define LOADK(d0_, d1_, g_) do { \
    const u16* kr_ = Kp + ((size_t)((g_)*32) + c31)*32 + hi*8; \
    d0_ = *(const bf16x8*)kr_; d1_ = *(const bf16x8*)(kr_ + 16); \
  } while(0)

#define GROUP_BODY(g_, k0_, k1_) do { \
    int kb_ = (g_) * 32; \
    bf16x8 bA0{}, bA1{}, bB0{}, bB1{}; \
    if (ROWMODE) { \
      const u16* bpA_ = biasF + ((((size_t)hh*8 + (g_))*8 + qtA)*2 + hi)*512 + (size_t)c31*16; \
      bA0 = *(const bf16x8*)bpA_; bA1 = *(const bf16x8*)(bpA_ + 8); \
    } \
    __builtin_amdgcn_s_setprio(1); \
    f32x16 sacA_ = __builtin_amdgcn_mfma_f32_32x32x16_bf16(k0_, qfA0, (f32x16)(0.0f), 0, 0, 0); \
    sacA_ = __builtin_amdgcn_mfma_f32_32x32x16_bf16(k1_, qfA1, sacA_, 0, 0, 0); \
    __builtin_amdgcn_s_setprio(0); \
    bf16x8 va0_ = *(const bf16x8*)&Vt[lh][c31][kb_ + hi*8]; \
    bf16x8 va1_ = *(const bf16x8*)&Vt[lh][c31][kb_ + 16 + hi*8]; \
    bf16x8 pf0_, pf1_; \
    softmax_pack<ROWMODE>(sacA_, lmb, bA0, bA1, kb_, hi, lsA, pf0_, pf1_); \
    __builtin_amdgcn_s_setprio(1); \
    oA = __builtin_amdgcn_mfma_f32_32x32x16_bf16(va0_, pf0_, oA, 0, 0, 0); \
    oA = __builtin_amdgcn_mfma_f32_32x32x16_bf16(va1_, pf1_, oA, 0, 0, 0); \
    __builtin_amdgcn_s_setprio(0); \
    if (ROWMODE) { \
      const u16* bpB_ = biasF + ((((size_t)hh*8 + (g_))*8 + qtB)*2 + hi)*512 + (size_t)c31*16; \
      bB0 = *(const bf16x8*)bpB_; bB1 = *(const bf16x8*)(bpB_ + 8); \
    } \
    __builtin_amdgcn_s_setprio(1); \
    f32x16 sacB_ = __builtin_amdgcn_mfma_f32_32x32x16_bf16(k0_, qfB0, (f32x16)(0.0f), 0, 0, 0); \
    sacB_ = __builtin_amdgcn_mfma_f32_32x32x16_bf16(k1_, qfB1, sacB_, 0, 0, 0); \
    __builtin_amdgcn_s_setprio(0); \
    softmax_pack<ROWMODE>(sacB_, lmb, bB0, bB1, kb_, hi, lsB, pf0_, pf1_); \
    __builtin_amdgcn_s_setprio(1); \
    oB = __builtin_amdgcn_mfma_f32_32x32x16_bf16(va0_, pf0_, oB, 0, 0, 0); \
    oB = __builtin_amdgcn_mfma_f32_32x32x16_bf16(va1_, pf1_, oB, 0, 0, 0); \
    __builtin_amdgcn_s_setprio(0); \
  } while(0)

  bf16x8 ke0{}, ke1{}, ko0{}, ko1{};
  LOADK(ke0, ke1, 0);
  LOADK(ko0, ko1, 1);
  for (int g = 0; g < NKV; g += 2) {
    bf16x8 c0 = ke0, c1 = ke1;
    if (g + 2 < NKV) LOADK(ke0, ke1, g + 2);
    GROUP_BODY(g, c0, c1);
    bf16x8 d0 = ko0, d1 = ko1;
    if (g + 3 < NKV) LOADK(ko0, ko1, g + 3);
    GROUP_BODY(g + 1, d0, d1);
  }
#undef GROUP_BODY
#undef LOADK

  lsA += __shfl_xor(lsA, 32);
  lsB += __shfl_xor(lsB, 32);
  float invA = 1.0f / lsA, invB = 1.0f / lsB;

  size_t baseO = (size_t)b * NKEY * 256 + (size_t)hh * 32;
  #pragma unroll
  for (int tile = 0; tile < 2; ++tile) {
    int q = (tile == 0) ? qA : qB;
    float inv = (tile == 0) ? invA : invB;
    const f32x16 &oo = (tile == 0) ? oA : oB;
    u16* op = og + baseO + (size_t)q * 256;
    const u16* gp = Gp + (size_t)q * 32;
    #pragma unroll
    for (int rq = 0; rq < 4; ++rq) {
      int c0 = 8*rq + 4*hi;
      ushort4 g4 = *(const ushort4*)(gp + c0);
      float f0 = oo[4*rq+0] * inv * bf2f(g4.x);
      float f1 = oo[4*rq+1] * inv * bf2f(g4.y);
      float f2 = oo[4*rq+2] * inv * bf2f(g4.z);
      float f3 = oo[4*rq+3] * inv * bf2f(g4.w);
      uint2 o2; o2.x = cvt_pk(f0, f1); o2.y = cvt_pk(f2, f3);
      *(uint2*)(op + c0) = o2;
    }
  }
}

extern "C" void kernel_launch(void* const* d_in, const int* in_sizes, int n_in,
                              void* d_out, int out_size, void* d_ws, size_t ws_size,
                              hipStream_t stream)
{
  const float* node         = (const float*)d_in[0];
  const float* pair         = (const float*)d_in[1];
  const float* node_mask    = (const float*)d_in[2];
  const float* row_ln_m_g   = (const float*)d_in[3];
  const float* row_ln_m_b   = (const float*)d_in[4];
  const float* row_ln_z_g   = (const float*)d_in[5];
  const float* row_ln_z_b   = (const float*)d_in[6];
  const float* row_b_w      = (const float*)d_in[7];
  const float* row_wq       = (const float*)d_in[8];
  const float* row_wk       = (const float*)d_in[9];
  const float* row_wv       = (const float*)d_in[10];
  const float* row_wg       = (const float*)d_in[11];
  const float* row_bg       = (const float*)d_in[12];
  const float* row_wo       = (const float*)d_in[13];
  const float* row_out_bias = (const float*)d_in[14];
  const float* col_ln_g     = (const float*)d_in[15];
  const float* col_ln_b     = (const float*)d_in[16];
  const float* col_wq       = (const float*)d_in[17];
  const float* col_wk       = (const float*)d_in[18];
  const float* col_wv       = (const float*)d_in[19];
  const float* col_wg       = (const float*)d_in[20];
  const float* col_bg       = (const float*)d_in[21];
  const float* col_wo       = (const float*)d_in[22];
  const float* col_bo       = (const float*)d_in[23];
  const float* tr_ln_g      = (const float*)d_in[24];
  const float* tr_ln_b      = (const float*)d_in[25];
  const float* tr_w1        = (const float*)d_in[26];
  const float* tr_b1        = (const float*)d_in[27];
  const float* tr_w2        = (const float*)d_in[28];
  const float* tr_b2        = (const float*)d_in[29];

  float* out = (float*)d_out;
  char* ws8 = (char*)d_ws;
  const size_t MB = 1ull << 20;
  u16*   A     = (u16*)(ws8);               // 16 MB  LN out [32768][256] bf16
  u16*   QKVG  = (u16*)(ws8 + 16*MB);       // 64 MB  head-major 32 x [32768][32] (also T1)
  u16*   Ob    = (u16*)(ws8 + 80*MB);       // 16 MB  gated attn out bf16 [row][256]
  u16*   DbF   = (u16*)(ws8 + 96*MB);       // 4 MB   bias fragments
  u16*   N1    = (u16*)(ws8 + 100*MB);      // 16 MB  node1 bf16 [s][r][256]
  u16*   N2    = (u16*)(ws8 + 116*MB);      // 16 MB  node2 bf16 [s][r][256]
  u16*   Wb    = (u16*)(ws8 + 132*MB);      // bf16 weight arena
  u16*   T1    = QKVG;

  const float qs = 0.17677669529663687f;    // 1/sqrt(32)

  u16* Wrqkvg = Wb + 0;
  u16* Wro    = Wb + 262144;
  u16* Wcqkvg = Wb + 327680;
  u16* Wco    = Wb + 589824;
  u16* W1w    = Wb + 655360;
  u16* W2w    = Wb + 917504;

  CvtArgs ca;
  const float* srcs[12] = {row_wq,row_wk,row_wv,row_wg,row_wo,
                           col_wq,col_wk,col_wv,col_wg,col_wo,tr_w1,tr_w2};
  int offs[12] = {0,65536,131072,196608,262144,327680,393216,458752,524288,589824,655360,917504};
  int ns[12]   = {65536,65536,65536,65536,65536,65536,65536,65536,65536,65536,262144,262144};
  for (int i = 0; i < 12; ++i) {
    ca.src[i] = srcs[i]; ca.off[i] = offs[i]; ca.n[i] = ns[i];
    ca.scale[i] = (i == 0 || i == 5) ? qs * LOG2E : 1.0f;
  }
  cvt_w_kernel<<<dim3(256,12), 256, 0, stream>>>(ca, Wb);

  dim3 g1024(8, 256);   // 128x128 tiles, N=1024 -> 2048 blocks
  dim3 g256(2, 256);    // 128x128 tiles, N=256  -> 512 blocks

  // --- row attention ---
  ln256_kernel<<<8192, 256, 0, stream>>>(node, A, row_ln_m_g, row_ln_m_b, 0, 0);
  pair_bias_kernel<<<4096, 256, 0, stream>>>(pair, row_ln_z_g, row_ln_z_b, row_b_w, DbF);
  gemm_v2<<<g1024, 256, 0, stream>>>(A, Wrqkvg, QKVG, 1024, 256, 6, row_bg, nullptr);
  attn_mfma<256,1,true><<<dim3(8,128), 256, 0, stream>>>(QKVG, DbF, node_mask, Ob);
  gemm_v2<<<g256, 256, 0, stream>>>(Ob, Wro, N1, 256, 256, 7, row_out_bias, node);

  // --- column attention (in [r,s,d] layout) ---
  ln256_kernel<<<8192, 256, 0, stream>>>(N1, A, col_ln_g, col_ln_b, 1, 1);
  gemm_v2<<<g1024, 256, 0, stream>>>(A, Wcqkvg, QKVG, 1024, 256, 6, col_bg, nullptr);
  attn_mfma<128,2,false><<<dim3(4,256), 256, 0, stream>>>(QKVG, nullptr, node_mask, Ob);
  gemm_v2<<<g256, 256, 0, stream>>>(Ob, Wco, N2, 256, 256, 8, col_bo, (const float*)N1);

  // --- transition ---
  ln256_kernel<<<8192, 256, 0, stream>>>(N2, A, tr_ln_g, tr_ln_b, 0, 1);
  gemm_v2<<<g1024, 256, 0, stream>>>(A, W1w, T1, 1024, 256, 3, tr_b1, nullptr);
  gemm_v2<<<g256, 256, 0, stream>>>(T1, W2w, out, 256, 1024, 9, tr_b2, (const float*)N2);
}

// Round 20
// 315.273 us; speedup vs baseline: 1.0036x; 1.0036x over previous
//
#include <hip/hip_runtime.h>
#include <math.h>

#define S 128
#define R 256
#define DMODEL 256
#define H 8
#define CDIM 32
#define HC 256
#define DFF 1024
#define NROWS (S*R)     // 32768
#define NPAIR (R*R)     // 65536
#define LN_EPS 1e-5f
#define LOG2E 1.4426950408889634f
#define M32 ((size_t)NROWS * 32)

typedef unsigned short u16;
typedef __attribute__((ext_vector_type(8))) short bf16x8;
typedef __attribute__((ext_vector_type(4))) float f32x4;
typedef __attribute__((ext_vector_type(16))) float f32x16;

__device__ __forceinline__ u16 f2bf(float x) {
  unsigned u = __float_as_uint(x);
  u = (u + 0x7fffu + ((u >> 16) & 1u)) >> 16;
  return (u16)u;
}
__device__ __forceinline__ float bf2f(u16 x) {
  return __uint_as_float(((unsigned)x) << 16);
}
__device__ __forceinline__ unsigned cvt_pk(float a, float b) {
  unsigned r;
  asm("v_cvt_pk_bf16_f32 %0, %1, %2" : "=v"(r) : "v"(a), "v"(b));
  return r;
}
__device__ __forceinline__ void pl32swap(unsigned &a, unsigned &b) {
  asm("v_permlane32_swap_b32 %0, %1" : "+v"(a), "+v"(b));
}
__device__ __forceinline__ bf16x8 mk_frag(unsigned a, unsigned b, unsigned c, unsigned d) {
  uint4 t = make_uint4(a, b, c, d);
  return __builtin_bit_cast(bf16x8, t);
}

__device__ __forceinline__ void gload_lds16(const u16* g, u16* l) {
  __builtin_amdgcn_global_load_lds(
      (const __attribute__((address_space(1))) unsigned int*)g,
      (__attribute__((address_space(3))) unsigned int*)l, 16, 0, 0);
}

// ---------------- weight f32 -> bf16 conversion (12 segments) ----------------
struct CvtArgs {
  const float* src[12];
  int off[12];
  int n[12];
  float scale[12];
};

__global__ __launch_bounds__(256) void cvt_w_kernel(CvtArgs a, u16* __restrict__ dst) {
  int sg = blockIdx.y;
  int i = (blockIdx.x * 256 + threadIdx.x) * 4;
  if (i >= a.n[sg]) return;
  float4 v = *(const float4*)(a.src[sg] + i);
  float sc = a.scale[sg];
  uint2 o;
  o.x = cvt_pk(v.x * sc, v.y * sc);
  o.y = cvt_pk(v.z * sc, v.w * sc);
  *(uint2*)(dst + a.off[sg] + i) = o;
}

// ---------------- LayerNorm over 256, one row per wave, bf16 out ----------------
__global__ __launch_bounds__(256) void ln256_kernel(
    const void* __restrict__ in, u16* __restrict__ out,
    const float* __restrict__ gamma, const float* __restrict__ beta,
    int tmode, int inbf)
{
  int wid = threadIdx.x >> 6, lane = threadIdx.x & 63;
  int m = blockIdx.x * 4 + wid;
  int inrow = m;
  if (tmode) { int r = m >> 7, s = m & 127; inrow = s * R + r; }
  float4 x;
  if (inbf) {
    ushort4 u = *(const ushort4*)((const u16*)in + (size_t)inrow * DMODEL + lane * 4);
    x.x = bf2f(u.x); x.y = bf2f(u.y); x.z = bf2f(u.z); x.w = bf2f(u.w);
  } else {
    x = *(const float4*)((const float*)in + (size_t)inrow * DMODEL + lane * 4);
  }
  float sum = x.x + x.y + x.z + x.w;
  float sq  = x.x*x.x + x.y*x.y + x.z*x.z + x.w*x.w;
  #pragma unroll
  for (int off = 32; off; off >>= 1) {
    sum += __shfl_xor(sum, off);
    sq  += __shfl_xor(sq, off);
  }
  float mean = sum * (1.0f/256.0f);
  float var  = sq  * (1.0f/256.0f) - mean*mean;
  float rstd = rsqrtf(var + LN_EPS);
  float4 g = *(const float4*)(gamma + lane*4);
  float4 b = *(const float4*)(beta  + lane*4);
  uint2 o;
  o.x = cvt_pk((x.x-mean)*rstd*g.x + b.x, (x.y-mean)*rstd*g.y + b.y);
  o.y = cvt_pk((x.z-mean)*rstd*g.z + b.z, (x.w-mean)*rstd*g.w + b.w);
  *(uint2*)(out + (size_t)m * DMODEL + lane*4) = o;
}

// -- pair LN (over 128) + bias projection -> FRAGMENT layout bias (bf16, *log2e) --
__global__ __launch_bounds__(256) void pair_bias_kernel(
    const float* __restrict__ pair, const float* __restrict__ gamma,
    const float* __restrict__ beta, const float* __restrict__ bw,
    u16* __restrict__ bias)
{
  int t = threadIdx.x;
  int lane = t & 63, wv = t >> 6;
  int sub = lane >> 4, l16 = lane & 15;
  int p = blockIdx.x * 16 + wv * 4 + sub;    // row index = q*256 + k
  const float* xp = pair + (size_t)p * 128 + l16 * 8;
  float4 x0 = *(const float4*)xp;
  float4 x1 = *(const float4*)(xp + 4);
  float xs[8] = {x0.x, x0.y, x0.z, x0.w, x1.x, x1.y, x1.z, x1.w};

  float sum = 0.f, sq = 0.f;
  #pragma unroll
  for (int j = 0; j < 8; ++j) { sum += xs[j]; sq += xs[j]*xs[j]; }
  #pragma unroll
  for (int d = 1; d < 16; d <<= 1) {
    sum += __shfl_xor(sum, d);
    sq  += __shfl_xor(sq, d);
  }
  float mean = sum * (1.0f/128.0f);
  float rstd = rsqrtf(sq*(1.0f/128.0f) - mean*mean + LN_EPS);

  const float* gp = gamma + l16*8;
  const float* bp = beta  + l16*8;
  float4 g0 = *(const float4*)gp, g1 = *(const float4*)(gp + 4);
  float4 b0 = *(const float4*)bp, b1 = *(const float4*)(bp + 4);
  float gg[8] = {g0.x,g0.y,g0.z,g0.w,g1.x,g1.y,g1.z,g1.w};
  float bb[8] = {b0.x,b0.y,b0.z,b0.w,b1.x,b1.y,b1.z,b1.w};
  float z[8];
  #pragma unroll
  for (int j = 0; j < 8; ++j) z[j] = (xs[j]-mean)*rstd*gg[j] + bb[j];

  float a[8];
  #pragma unroll
  for (int h = 0; h < 8; ++h) {
    const float* wp = bw + h*128 + l16*8;
    float4 w0 = *(const float4*)wp, w1 = *(const float4*)(wp + 4);
    a[h] = z[0]*w0.x + z[1]*w0.y + z[2]*w0.z + z[3]*w0.w
         + z[4]*w1.x + z[5]*w1.y + z[6]*w1.z + z[7]*w1.w;
  }

  #pragma unroll
  for (int i = 0; i < 4; ++i) {
    float send = (lane & 1) ? a[i] : a[i+4];
    float recv = __shfl_xor(send, 1);
    a[i] = ((lane & 1) ? a[i+4] : a[i]) + recv;
  }
  #pragma unroll
  for (int i = 0; i < 2; ++i) {
    float send = (lane & 2) ? a[i] : a[i+2];
    float recv = __shfl_xor(send, 2);
    a[i] = ((lane & 2) ? a[i+2] : a[i]) + recv;
  }
  {
    float send = (lane & 4) ? a[0] : a[1];
    float recv = __shfl_xor(send, 4);
    a[0] = ((lane & 4) ? a[1] : a[0]) + recv;
  }
  a[0] += __shfl_xor(a[0], 8);
  int h = 4*(l16 & 1) + (l16 & 2) + ((l16 >> 2) & 1);

  if (l16 < 8) {
    int q = p >> 8, k = p & 255;
    int kt = k >> 5, qt = q >> 5, c31 = q & 31;
    int kk = k & 31;
    int hi2 = (kk >> 2) & 1;
    int j = (kk & 3) | ((kk >> 3) << 2);
    size_t addr = ((((size_t)h*8 + kt)*8 + qt)*2 + hi2)*512 + (size_t)c31*16 + j;
    bias[addr] = f2bf(a[0] * LOG2E);
  }
}

// ---------- shared epilogue for one (row, col0, f32x4) output quad ----------
__device__ __forceinline__ void epi_store(
    int mode, void* __restrict__ Cout, int N,
    const float* __restrict__ bias, const float* __restrict__ res,
    int row, int col0, f32x4 v)
{
  const u16* resb = (const u16*)res;
  if (mode == 6) {
    if (col0 >= 768) {
      float4 b4 = *(const float4*)(bias + col0 - 768);
      v[0] = 1.0f/(1.0f+__expf(-(v[0]+b4.x)));
      v[1] = 1.0f/(1.0f+__expf(-(v[1]+b4.y)));
      v[2] = 1.0f/(1.0f+__expf(-(v[2]+b4.z)));
      v[3] = 1.0f/(1.0f+__expf(-(v[3]+b4.w)));
    }
    uint2 o; o.x = cvt_pk(v[0], v[1]); o.y = cvt_pk(v[2], v[3]);
    size_t i2 = (size_t)(col0 >> 5) * M32 + (size_t)row*32 + (col0 & 31);
    *(uint2*)((u16*)Cout + i2) = o;
  } else if (mode == 3) {
    float4 b4 = *(const float4*)(bias + col0);
    uint2 o;
    o.x = cvt_pk(fmaxf(v[0]+b4.x, 0.f), fmaxf(v[1]+b4.y, 0.f));
    o.y = cvt_pk(fmaxf(v[2]+b4.z, 0.f), fmaxf(v[3]+b4.w, 0.f));
    *(uint2*)((u16*)Cout + (size_t)row*N + col0) = o;
  } else if (mode == 7) {
    size_t i2 = (size_t)row*N + col0;
    float4 r4 = *(const float4*)(res + i2);
    float4 b4 = *(const float4*)(bias + col0);
    uint2 o;
    o.x = cvt_pk(v[0]+r4.x+b4.x, v[1]+r4.y+b4.y);
    o.y = cvt_pk(v[2]+r4.z+b4.z, v[3]+r4.w+b4.w);
    *(uint2*)((u16*)Cout + i2) = o;
  } else if (mode == 8) {
    int rr = row >> 7, ss = row & 127;
    size_t i2 = ((size_t)ss*R + rr)*(size_t)N + col0;
    ushort4 r4 = *(const ushort4*)(resb + i2);
    float4 b4 = *(const float4*)(bias + col0);
    uint2 o;
    o.x = cvt_pk(v[0]+bf2f(r4.x)+b4.x, v[1]+bf2f(r4.y)+b4.y);
    o.y = cvt_pk(v[2]+bf2f(r4.z)+b4.z, v[3]+bf2f(r4.w)+b4.w);
    *(uint2*)((u16*)Cout + i2) = o;
  } else if (mode == 9) {
    size_t i2 = (size_t)row*N + col0;
    ushort4 r4 = *(const ushort4*)(resb + i2);
    float4 b4 = *(const float4*)(bias + col0);
    float4 o = make_float4(v[0]+bf2f(r4.x)+b4.x, v[1]+bf2f(r4.y)+b4.y,
                           v[2]+bf2f(r4.z)+b4.z, v[3]+bf2f(r4.w)+b4.w);
    *(float4*)((float*)Cout + i2) = o;
  } else {
    uint2 o; o.x = cvt_pk(v[0], v[1]); o.y = cvt_pk(v[2], v[3]);
    *(uint2*)((u16*)Cout + (size_t)row*N + col0) = o;
  }
}

// ---------------- bf16 MFMA NT GEMM v2: 128x128 tile, 256 thr / 4 waves, BK=32 ----
// AHM: A input is head-major (32-col chunks of [NROWS][32], e.g. attn output Ob).
__global__ __launch_bounds__(256, 4) void gemm_v2(
    const u16* __restrict__ A, const u16* __restrict__ W,
    void* __restrict__ Cout, int N, int K,
    int mode, const float* __restrict__ bias, const float* __restrict__ res,
    int ahm)
{
  __shared__ u16 lds[2][2][128*32];
  int t = threadIdx.x, lane = t & 63, wv = t >> 6;
  int g16 = (lane >> 4) & 3, l16 = lane & 15;
  int wm = wv >> 1, wn = wv & 1;

  int gx = gridDim.x;
  int nwg = gx * gridDim.y;
  int p = blockIdx.y * gx + blockIdx.x;
  int cpx = nwg >> 3;
  int lg = (p & 7) * cpx + (p >> 3);
  int bn = (lg % gx) * 128;
  int bm = (lg / gx) * 128;

  int sr = t >> 2;
  int swz8 = ((t & 3) ^ ((sr >> 1) & 3)) << 3;
  int rdch = (g16 ^ ((l16 >> 1) & 3)) << 3;
  int rdoff = l16 * 32 + rdch;

  f32x4 acc[4][4];
  #pragma unroll
  for (int i = 0; i < 4; ++i)
    #pragma unroll
    for (int j = 0; j < 4; ++j) acc[i][j] = (f32x4){0.f,0.f,0.f,0.f};

  const int nkt = K >> 5;

#define STAGE(buf_, kc_) do { \
    const u16* a0p = ahm ? (A + (size_t)((kc_) >> 5) * M32 + (size_t)(bm + sr) * 32 + swz8) \
                         : (A + (size_t)(bm + sr) * K + (kc_) + swz8); \
    const u16* a1p = ahm ? (A + (size_t)((kc_) >> 5) * M32 + (size_t)(bm + 64 + sr) * 32 + swz8) \
                         : (A + (size_t)(bm + 64 + sr) * K + (kc_) + swz8); \
    gload_lds16(a0p, &lds[buf_][0][t*8]); \
    gload_lds16(a1p, &lds[buf_][0][2048 + t*8]); \
    gload_lds16(W + (size_t)(bn + sr) * K + (kc_) + swz8, &lds[buf_][1][t*8]); \
    gload_lds16(W + (size_t)(bn + 64 + sr) * K + (kc_) + swz8, &lds[buf_][1][2048 + t*8]); \
  } while(0)

  STAGE(0, 0);
  for (int kt = 0; kt < nkt; ++kt) {
    if (kt + 1 < nkt) {
      STAGE((kt + 1) & 1, (kt + 1) * 32);
      asm volatile("s_waitcnt vmcnt(4)" ::: "memory");
    } else {
      asm volatile("s_waitcnt vmcnt(0)" ::: "memory");
    }
    __builtin_amdgcn_s_barrier();
    int buf = kt & 1;
    const u16* Abase = &lds[buf][0][wm*2048];
    const u16* Wbase = &lds[buf][1][wn*2048];
    bf16x8 wf[4];
    #pragma unroll
    for (int nf = 0; nf < 4; ++nf)
      wf[nf] = *(const bf16x8*)(Wbase + nf*512 + rdoff);
    __builtin_amdgcn_s_setprio(1);
    #pragma unroll
    for (int mf = 0; mf < 4; ++mf) {
      bf16x8 a0 = *(const bf16x8*)(Abase + mf*512 + rdoff);
      #pragma unroll
      for (int nf = 0; nf < 4; ++nf)
        acc[mf][nf] = __builtin_amdgcn_mfma_f32_16x16x32_bf16(wf[nf], a0, acc[mf][nf], 0, 0, 0);
    }
    __builtin_amdgcn_s_setprio(0);
    asm volatile("" ::: "memory");
    __builtin_amdgcn_s_barrier();
  }
#undef STAGE

  int rowb = bm + wm*64 + l16;
  int colb = bn + wn*64 + (g16 << 2);
  #pragma unroll
  for (int mf = 0; mf < 4; ++mf) {
    int row = rowb + mf*16;
    #pragma unroll
    for (int nf = 0; nf < 4; ++nf)
      epi_store(mode, Cout, N, bias, res, row, colb + nf*16, acc[mf][nf]);
  }
}

// ---- softmax + pack: bias comes pre-packed in fragment order (2x bf16x8) ----
template<bool RM>
__device__ __forceinline__ void softmax_pack(
    const f32x16 &sac, const float* __restrict__ lmbp,
    bf16x8 bf0, bf16x8 bf1, int kb, int hi,
    float &lsum, bf16x8 &pf0, bf16x8 &pf1)
{
  float p[16];
  #pragma unroll
  for (int rq = 0; rq < 4; ++rq) {
    int k0 = kb + 8*rq + 4*hi;
    float4 lm4 = *(const float4*)&lmbp[k0];
    float b0 = lm4.x, b1 = lm4.y, b2 = lm4.z, b3 = lm4.w;
    if (RM) {
      if (rq < 2) {
        b0 += bf2f((u16)bf0[4*rq+0]); b1 += bf2f((u16)bf0[4*rq+1]);
        b2 += bf2f((u16)bf0[4*rq+2]); b3 += bf2f((u16)bf0[4*rq+3]);
      } else {
        b0 += bf2f((u16)bf1[4*rq-8+0]); b1 += bf2f((u16)bf1[4*rq-8+1]);
        b2 += bf2f((u16)bf1[4*rq-8+2]); b3 += bf2f((u16)bf1[4*rq-8+3]);
      }
    }
    p[4*rq+0] = exp2f(sac[4*rq+0] + b0);
    p[4*rq+1] = exp2f(sac[4*rq+1] + b1);
    p[4*rq+2] = exp2f(sac[4*rq+2] + b2);
    p[4*rq+3] = exp2f(sac[4*rq+3] + b3);
    lsum += (p[4*rq+0] + p[4*rq+1]) + (p[4*rq+2] + p[4*rq+3]);
  }
  unsigned u0 = cvt_pk(p[0],  p[1]),  u1 = cvt_pk(p[2],  p[3]);
  unsigned u2 = cvt_pk(p[4],  p[5]),  u3 = cvt_pk(p[6],  p[7]);
  unsigned u4 = cvt_pk(p[8],  p[9]),  u5 = cvt_pk(p[10], p[11]);
  unsigned u6 = cvt_pk(p[12], p[13]), u7 = cvt_pk(p[14], p[15]);
  pl32swap(u0, u2); pl32swap(u1, u3);
  pl32swap(u4, u6); pl32swap(u5, u7);
  pf0 = mk_frag(u0, u1, u2, u3);
  pf1 = mk_frag(u4, u5, u6, u7);
}

// ---------------- MFMA attention, 32x32, 256 thr / 4 waves, head-major QKVG+Ob ----
// HPB heads per block; WPH = 4/HPB waves per head; each wave owns 2 q-tiles (64 q).
// O output head-major: Ob[h][row][32] -- dense 64B-line writes per lane.
template<int NKEY, int HPB, bool ROWMODE>
__global__ __launch_bounds__(256, 4) void attn_mfma(
    const u16* __restrict__ QKVG, const u16* __restrict__ biasF,
    const float* __restrict__ mask, u16* __restrict__ og)
{
  __shared__ __align__(16) u16 Vt[HPB][32][NKEY + 8];
  __shared__ float lmb[NKEY];
  constexpr int NKV = NKEY / 32;
  constexpr int WPH = 4 / HPB;
  int b = blockIdx.y;
  int t = threadIdx.x, lane = t & 63, w = t >> 6;
  int c31 = lane & 31, hi = lane >> 5;
  int lh = w / WPH, wtile = w % WPH;
  int hh = blockIdx.x * HPB + lh;

  size_t rbase = (size_t)b * NKEY * 32;
  const u16* Qp = QKVG + (size_t)hh * M32 + rbase;
  const u16* Kp = QKVG + (size_t)(8 + hh) * M32 + rbase;
  const u16* Gp = QKVG + (size_t)(24 + hh) * M32 + rbase;

  for (int i = t; i < HPB*NKEY*4; i += 256) {
    int c0 = (i & 3) * 8;
    int key = (i >> 2) & (NKEY - 1);
    int sh = (i >> 2) / NKEY;
    const u16* Vs = QKVG + (size_t)(16 + blockIdx.x*HPB + sh) * M32 + rbase;
    bf16x8 v8 = *(const bf16x8*)(Vs + (size_t)key*32 + c0);
    #pragma unroll
    for (int j = 0; j < 8; ++j) Vt[sh][c0+j][key] = (u16)v8[j];
  }
  for (int i = t; i < NKEY; i += 256)
    lmb[i] = 1.4426950e9f * ((ROWMODE ? mask[b*R + i] : mask[i*R + b]) - 1.0f);
  __syncthreads();

  int qA = wtile*64 + c31, qB = qA + 32;
  int qtA = wtile*2, qtB = wtile*2 + 1;
  bf16x8 qfA0 = *(const bf16x8*)(Qp + (size_t)qA*32 + hi*8);
  bf16x8 qfA1 = *(const bf16x8*)(Qp + (size_t)qA*32 + 16 + hi*8);
  bf16x8 qfB0 = *(const bf16x8*)(Qp + (size_t)qB*32 + hi*8);
  bf16x8 qfB1 = *(const bf16x8*)(Qp + (size_t)qB*32 + 16 + hi*8);

  f32x16 oA = (f32x16)(0.0f), oB = (f32x16)(0.0f);
  float lsA = 0.f, lsB = 0.f;

#define LOADK(d0_, d1_, g_) do { \
    const u16* kr_ = Kp + ((size_t)((g_)*32) + c31)*32 + hi*8; \
    d0_ = *(const bf16x8*)kr_; d1_ = *(const bf16x8*)(kr_ + 16); \
  } while(0)

#define GROUP_BODY(g_, k0_, k1_) do { \
    int kb_ = (g_) * 32; \
    bf16x8 bA0{}, bA1{}, bB0{}, bB1{}; \
    if (ROWMODE) { \
      const u16* bpA_ = biasF + ((((size_t)hh*8 + (g_))*8 + qtA)*2 + hi)*512 + (size_t)c31*16; \
      bA0 = *(const bf16x8*)bpA_; bA1 = *(const bf16x8*)(bpA_ + 8); \
    } \
    __builtin_amdgcn_s_setprio(1); \
    f32x16 sacA_ = __builtin_amdgcn_mfma_f32_32x32x16_bf16(k0_, qfA0, (f32x16)(0.0f), 0, 0, 0); \
    sacA_ = __builtin_amdgcn_mfma_f32_32x32x16_bf16(k1_, qfA1, sacA_, 0, 0, 0); \
    __builtin_amdgcn_s_setprio(0); \
    bf16x8 va0_ = *(const bf16x8*)&Vt[lh][c31][kb_ + hi*8]; \
    bf16x8 va1_ = *(const bf16x8*)&Vt[lh][c31][kb_ + 16 + hi*8]; \
    bf16x8 pf0_, pf1_; \
    softmax_pack<ROWMODE>(sacA_, lmb, bA0, bA1, kb_, hi, lsA, pf0_, pf1_); \
    __builtin_amdgcn_s_setprio(1); \
    oA = __builtin_amdgcn_mfma_f32_32x32x16_bf16(va0_, pf0_, oA, 0, 0, 0); \
    oA = __builtin_amdgcn_mfma_f32_32x32x16_bf16(va1_, pf1_, oA, 0, 0, 0); \
    __builtin_amdgcn_s_setprio(0); \
    if (ROWMODE) { \
      const u16* bpB_ = biasF + ((((size_t)hh*8 + (g_))*8 + qtB)*2 + hi)*512 + (size_t)c31*16; \
      bB0 = *(const bf16x8*)bpB_; bB1 = *(const bf16x8*)(bpB_ + 8); \
    } \
    __builtin_amdgcn_s_setprio(1); \
    f32x16 sacB_ = __builtin_amdgcn_mfma_f32_32x32x16_bf16(k0_, qfB0, (f32x16)(0.0f), 0, 0, 0); \
    sacB_ = __builtin_amdgcn_mfma_f32_32x32x16_bf16(k1_, qfB1, sacB_, 0, 0, 0); \
    __builtin_amdgcn_s_setprio(0); \
    softmax_pack<ROWMODE>(sacB_, lmb, bB0, bB1, kb_, hi, lsB, pf0_, pf1_); \
    __builtin_amdgcn_s_setprio(1); \
    oB = __builtin_amdgcn_mfma_f32_32x32x16_bf16(va0_, pf0_, oB, 0, 0, 0); \
    oB = __builtin_amdgcn_mfma_f32_32x32x16_bf16(va1_, pf1_, oB, 0, 0, 0); \
    __builtin_amdgcn_s_setprio(0); \
  } while(0)

  bf16x8 ke0{}, ke1{}, ko0{}, ko1{};
  LOADK(ke0, ke1, 0);
  LOADK(ko0, ko1, 1);
  for (int g = 0; g < NKV; g += 2) {
    bf16x8 c0 = ke0, c1 = ke1;
    if (g + 2 < NKV) LOADK(ke0, ke1, g + 2);
    GROUP_BODY(g, c0, c1);
    bf16x8 d0 = ko0, d1 = ko1;
    if (g + 3 < NKV) LOADK(ko0, ko1, g + 3);
    GROUP_BODY(g + 1, d0, d1);
  }
#undef GROUP_BODY
#undef LOADK

  lsA += __shfl_xor(lsA, 32);
  lsB += __shfl_xor(lsB, 32);
  float invA = 1.0f / lsA, invB = 1.0f / lsB;

  // head-major O store: og[hh][b*NKEY + q][32]
  size_t baseO = (size_t)hh * M32 + rbase;
  #pragma unroll
  for (int tile = 0; tile < 2; ++tile) {
    int q = (tile == 0) ? qA : qB;
    float inv = (tile == 0) ? invA : invB;
    const f32x16 &oo = (tile == 0) ? oA : oB;
    u16* op = og + baseO + (size_t)q * 32;
    const u16* gp = Gp + (size_t)q * 32;
    #pragma unroll
    for (int rq = 0; rq < 4; ++rq) {
      int c0 = 8*rq + 4*hi;
      ushort4 g4 = *(const ushort4*)(gp + c0);
      float f0 = oo[4*rq+0] * inv * bf2f(g4.x);
      float f1 = oo[4*rq+1] * inv * bf2f(g4.y);
      float f2 = oo[4*rq+2] * inv * bf2f(g4.z);
      float f3 = oo[4*rq+3] * inv * bf2f(g4.w);
      uint2 o2; o2.x = cvt_pk(f0, f1); o2.y = cvt_pk(f2, f3);
      *(uint2*)(op + c0) = o2;
    }
  }
}

extern "C" void kernel_launch(void* const* d_in, const int* in_sizes, int n_in,
                              void* d_out, int out_size, void* d_ws, size_t ws_size,
                              hipStream_t stream)
{
  const float* node         = (const float*)d_in[0];
  const float* pair         = (const float*)d_in[1];
  const float* node_mask    = (const float*)d_in[2];
  const float* row_ln_m_g   = (const float*)d_in[3];
  const float* row_ln_m_b   = (const float*)d_in[4];
  const float* row_ln_z_g   = (const float*)d_in[5];
  const float* row_ln_z_b   = (const float*)d_in[6];
  const float* row_b_w      = (const float*)d_in[7];
  const float* row_wq       = (const float*)d_in[8];
  const float* row_wk       = (const float*)d_in[9];
  const float* row_wv       = (const float*)d_in[10];
  const float* row_wg       = (const float*)d_in[11];
  const float* row_bg       = (const float*)d_in[12];
  const float* row_wo       = (const float*)d_in[13];
  const float* row_out_bias = (const float*)d_in[14];
  const float* col_ln_g     = (const float*)d_in[15];
  const float* col_ln_b     = (const float*)d_in[16];
  const float* col_wq       = (const float*)d_in[17];
  const float* col_wk       = (const float*)d_in[18];
  const float* col_wv       = (const float*)d_in[19];
  const float* col_wg       = (const float*)d_in[20];
  const float* col_bg       = (const float*)d_in[21];
  const float* col_wo       = (const float*)d_in[22];
  const float* col_bo       = (const float*)d_in[23];
  const float* tr_ln_g      = (const float*)d_in[24];
  const float* tr_ln_b      = (const float*)d_in[25];
  const float* tr_w1        = (const float*)d_in[26];
  const float* tr_b1        = (const float*)d_in[27];
  const float* tr_w2        = (const float*)d_in[28];
  const float* tr_b2        = (const float*)d_in[29];

  float* out = (float*)d_out;
  char* ws8 = (char*)d_ws;
  const size_t MB = 1ull << 20;
  u16*   A     = (u16*)(ws8);               // 16 MB  LN out [32768][256] bf16
  u16*   QKVG  = (u16*)(ws8 + 16*MB);       // 64 MB  head-major 32 x [32768][32] (also T1)
  u16*   Ob    = (u16*)(ws8 + 80*MB);       // 16 MB  attn out, head-major 8 x [32768][32]
  u16*   DbF   = (u16*)(ws8 + 96*MB);       // 4 MB   bias fragments
  u16*   N1    = (u16*)(ws8 + 100*MB);      // 16 MB  node1 bf16 [s][r][256]
  u16*   N2    = (u16*)(ws8 + 116*MB);      // 16 MB  node2 bf16 [s][r][256]
  u16*   Wb    = (u16*)(ws8 + 132*MB);      // bf16 weight arena
  u16*   T1    = QKVG;

  const float qs = 0.17677669529663687f;    // 1/sqrt(32)

  u16* Wrqkvg = Wb + 0;
  u16* Wro    = Wb + 262144;
  u16* Wcqkvg = Wb + 327680;
  u16* Wco    = Wb + 589824;
  u16* W1w    = Wb + 655360;
  u16* W2w    = Wb + 917504;

  CvtArgs ca;
  const float* srcs[12] = {row_wq,row_wk,row_wv,row_wg,row_wo,
                           col_wq,col_wk,col_wv,col_wg,col_wo,tr_w1,tr_w2};
  int offs[12] = {0,65536,131072,196608,262144,327680,393216,458752,524288,589824,655360,917504};
  int ns[12]   = {65536,65536,65536,65536,65536,65536,65536,65536,65536,65536,262144,262144};
  for (int i = 0; i < 12; ++i) {
    ca.src[i] = srcs[i]; ca.off[i] = offs[i]; ca.n[i] = ns[i];
    ca.scale[i] = (i == 0 || i == 5) ? qs * LOG2E : 1.0f;
  }
  cvt_w_kernel<<<dim3(256,12), 256, 0, stream>>>(ca, Wb);

  dim3 g1024(8, 256);   // 128x128 tiles, N=1024 -> 2048 blocks
  dim3 g256(2, 256);    // 128x128 tiles, N=256  -> 512 blocks

  // --- row attention ---
  ln256_kernel<<<8192, 256, 0, stream>>>(node, A, row_ln_m_g, row_ln_m_b, 0, 0);
  pair_bias_kernel<<<4096, 256, 0, stream>>>(pair, row_ln_z_g, row_ln_z_b, row_b_w, DbF);
  gemm_v2<<<g1024, 256, 0, stream>>>(A, Wrqkvg, QKVG, 1024, 256, 6, row_bg, nullptr, 0);
  attn_mfma<256,1,true><<<dim3(8,128), 256, 0, stream>>>(QKVG, DbF, node_mask, Ob);
  gemm_v2<<<g256, 256, 0, stream>>>(Ob, Wro, N1, 256, 256, 7, row_out_bias, node, 1);

  // --- column attention (in [r,s,d] layout) ---
  ln256_kernel<<<8192, 256, 0, stream>>>(N1, A, col_ln_g, col_ln_b, 1, 1);
  gemm_v2<<<g1024, 256, 0, stream>>>(A, Wcqkvg, QKVG, 1024, 256, 6, col_bg, nullptr, 0);
  attn_mfma<128,2,false><<<dim3(4,256), 256, 0, stream>>>(QKVG, nullptr, node_mask, Ob);
  gemm_v2<<<g256, 256, 0, stream>>>(Ob, Wco, N2, 256, 256, 8, col_bo, (const float*)N1, 1);

  // --- transition ---
  ln256_kernel<<<8192, 256, 0, stream>>>(N2, A, tr_ln_g, tr_ln_b, 0, 1);
  gemm_v2<<<g1024, 256, 0, stream>>>(A, W1w, T1, 1024, 256, 3, tr_b1, nullptr, 0);
  gemm_v2<<<g256, 256, 0, stream>>>(T1, W2w, out, 256, 1024, 9, tr_b2, (const float*)N2, 0);
}

// Round 21
// 286.282 us; speedup vs baseline: 1.1053x; 1.1013x over previous
//
#include <hip/hip_runtime.h>
#include <math.h>

#define S 128
#define R 256
#define DMODEL 256
#define H 8
#define CDIM 32
#define HC 256
#define DFF 1024
#define NROWS (S*R)     // 32768
#define NPAIR (R*R)     // 65536
#define LN_EPS 1e-5f
#define LOG2E 1.4426950408889634f
#define M32 ((size_t)NROWS * 32)

typedef unsigned short u16;
typedef __attribute__((ext_vector_type(8))) short bf16x8;
typedef __attribute__((ext_vector_type(4))) float f32x4;
typedef __attribute__((ext_vector_type(16))) float f32x16;

__device__ __forceinline__ u16 f2bf(float x) {
  unsigned u = __float_as_uint(x);
  u = (u + 0x7fffu + ((u >> 16) & 1u)) >> 16;
  return (u16)u;
}
__device__ __forceinline__ float bf2f(u16 x) {
  return __uint_as_float(((unsigned)x) << 16);
}
__device__ __forceinline__ unsigned cvt_pk(float a, float b) {
  unsigned r;
  asm("v_cvt_pk_bf16_f32 %0, %1, %2" : "=v"(r) : "v"(a), "v"(b));
  return r;
}
__device__ __forceinline__ void pl32swap(unsigned &a, unsigned &b) {
  asm("v_permlane32_swap_b32 %0, %1" : "+v"(a), "+v"(b));
}
__device__ __forceinline__ bf16x8 mk_frag(unsigned a, unsigned b, unsigned c, unsigned d) {
  uint4 t = make_uint4(a, b, c, d);
  return __builtin_bit_cast(bf16x8, t);
}

__device__ __forceinline__ void gload_lds16(const u16* g, u16* l) {
  __builtin_amdgcn_global_load_lds(
      (const __attribute__((address_space(1))) unsigned int*)g,
      (__attribute__((address_space(3))) unsigned int*)l, 16, 0, 0);
}

// ---------------- weight f32 -> bf16 conversion (12 segments) ----------------
struct CvtArgs {
  const float* src[12];
  int off[12];
  int n[12];
  float scale[12];
};

__global__ __launch_bounds__(256) void cvt_w_kernel(CvtArgs a, u16* __restrict__ dst) {
  int sg = blockIdx.y;
  int i = (blockIdx.x * 256 + threadIdx.x) * 4;
  if (i >= a.n[sg]) return;
  float4 v = *(const float4*)(a.src[sg] + i);
  float sc = a.scale[sg];
  uint2 o;
  o.x = cvt_pk(v.x * sc, v.y * sc);
  o.y = cvt_pk(v.z * sc, v.w * sc);
  *(uint2*)(dst + a.off[sg] + i) = o;
}

// ---------------- LayerNorm over 256, one row per wave, bf16 out ----------------
__global__ __launch_bounds__(256) void ln256_kernel(
    const void* __restrict__ in, u16* __restrict__ out,
    const float* __restrict__ gamma, const float* __restrict__ beta,
    int tmode, int inbf)
{
  int wid = threadIdx.x >> 6, lane = threadIdx.x & 63;
  int m = blockIdx.x * 4 + wid;
  int inrow = m;
  if (tmode) { int r = m >> 7, s = m & 127; inrow = s * R + r; }
  float4 x;
  if (inbf) {
    ushort4 u = *(const ushort4*)((const u16*)in + (size_t)inrow * DMODEL + lane * 4);
    x.x = bf2f(u.x); x.y = bf2f(u.y); x.z = bf2f(u.z); x.w = bf2f(u.w);
  } else {
    x = *(const float4*)((const float*)in + (size_t)inrow * DMODEL + lane * 4);
  }
  float sum = x.x + x.y + x.z + x.w;
  float sq  = x.x*x.x + x.y*x.y + x.z*x.z + x.w*x.w;
  #pragma unroll
  for (int off = 32; off; off >>= 1) {
    sum += __shfl_xor(sum, off);
    sq  += __shfl_xor(sq, off);
  }
  float mean = sum * (1.0f/256.0f);
  float var  = sq  * (1.0f/256.0f) - mean*mean;
  float rstd = rsqrtf(var + LN_EPS);
  float4 g = *(const float4*)(gamma + lane*4);
  float4 b = *(const float4*)(beta  + lane*4);
  uint2 o;
  o.x = cvt_pk((x.x-mean)*rstd*g.x + b.x, (x.y-mean)*rstd*g.y + b.y);
  o.y = cvt_pk((x.z-mean)*rstd*g.z + b.z, (x.w-mean)*rstd*g.w + b.w);
  *(uint2*)(out + (size_t)m * DMODEL + lane*4) = o;
}

// -- pair LN (over 128) + bias projection -> FRAGMENT layout bias (bf16, *log2e) --
// 16 lanes per row, 4 rows per wave, 16 rows per block.
__global__ __launch_bounds__(256) void pair_bias_kernel(
    const float* __restrict__ pair, const float* __restrict__ gamma,
    const float* __restrict__ beta, const float* __restrict__ bw,
    u16* __restrict__ bias)
{
  int t = threadIdx.x;
  int lane = t & 63, wv = t >> 6;
  int sub = lane >> 4, l16 = lane & 15;
  int p = blockIdx.x * 16 + wv * 4 + sub;    // row index = q*256 + k
  const float* xp = pair + (size_t)p * 128 + l16 * 8;
  float4 x0 = *(const float4*)xp;
  float4 x1 = *(const float4*)(xp + 4);
  float xs[8] = {x0.x, x0.y, x0.z, x0.w, x1.x, x1.y, x1.z, x1.w};

  float sum = 0.f, sq = 0.f;
  #pragma unroll
  for (int j = 0; j < 8; ++j) { sum += xs[j]; sq += xs[j]*xs[j]; }
  #pragma unroll
  for (int d = 1; d < 16; d <<= 1) {
    sum += __shfl_xor(sum, d);
    sq  += __shfl_xor(sq, d);
  }
  float mean = sum * (1.0f/128.0f);
  float rstd = rsqrtf(sq*(1.0f/128.0f) - mean*mean + LN_EPS);

  const float* gp = gamma + l16*8;
  const float* bp = beta  + l16*8;
  float4 g0 = *(const float4*)gp, g1 = *(const float4*)(gp + 4);
  float4 b0 = *(const float4*)bp, b1 = *(const float4*)(bp + 4);
  float gg[8] = {g0.x,g0.y,g0.z,g0.w,g1.x,g1.y,g1.z,g1.w};
  float bb[8] = {b0.x,b0.y,b0.z,b0.w,b1.x,b1.y,b1.z,b1.w};
  float z[8];
  #pragma unroll
  for (int j = 0; j < 8; ++j) z[j] = (xs[j]-mean)*rstd*gg[j] + bb[j];

  float a[8];
  #pragma unroll
  for (int h = 0; h < 8; ++h) {
    const float* wp = bw + h*128 + l16*8;
    float4 w0 = *(const float4*)wp, w1 = *(const float4*)(wp + 4);
    a[h] = z[0]*w0.x + z[1]*w0.y + z[2]*w0.z + z[3]*w0.w
         + z[4]*w1.x + z[5]*w1.y + z[6]*w1.z + z[7]*w1.w;
  }

  #pragma unroll
  for (int i = 0; i < 4; ++i) {
    float send = (lane & 1) ? a[i] : a[i+4];
    float recv = __shfl_xor(send, 1);
    a[i] = ((lane & 1) ? a[i+4] : a[i]) + recv;
  }
  #pragma unroll
  for (int i = 0; i < 2; ++i) {
    float send = (lane & 2) ? a[i] : a[i+2];
    float recv = __shfl_xor(send, 2);
    a[i] = ((lane & 2) ? a[i+2] : a[i]) + recv;
  }
  {
    float send = (lane & 4) ? a[0] : a[1];
    float recv = __shfl_xor(send, 4);
    a[0] = ((lane & 4) ? a[1] : a[0]) + recv;
  }
  a[0] += __shfl_xor(a[0], 8);
  int h = 4*(l16 & 1) + (l16 & 2) + ((l16 >> 2) & 1);

  if (l16 < 8) {
    int q = p >> 8, k = p & 255;
    int kt = k >> 5, qt = q >> 5, c31 = q & 31;
    int kk = k & 31;
    int hi2 = (kk >> 2) & 1;
    int j = (kk & 3) | ((kk >> 3) << 2);
    size_t addr = ((((size_t)h*8 + kt)*8 + qt)*2 + hi2)*512 + (size_t)c31*16 + j;
    bias[addr] = f2bf(a[0] * LOG2E);
  }
}

// ---------- shared epilogue for one (row, col0, f32x4) output quad ----------
__device__ __forceinline__ void epi_store(
    int mode, void* __restrict__ Cout, int N,
    const float* __restrict__ bias, const float* __restrict__ res,
    int row, int col0, f32x4 v)
{
  const u16* resb = (const u16*)res;
  if (mode == 6) {
    if (col0 >= 768) {
      float4 b4 = *(const float4*)(bias + col0 - 768);
      v[0] = 1.0f/(1.0f+__expf(-(v[0]+b4.x)));
      v[1] = 1.0f/(1.0f+__expf(-(v[1]+b4.y)));
      v[2] = 1.0f/(1.0f+__expf(-(v[2]+b4.z)));
      v[3] = 1.0f/(1.0f+__expf(-(v[3]+b4.w)));
    }
    uint2 o; o.x = cvt_pk(v[0], v[1]); o.y = cvt_pk(v[2], v[3]);
    size_t i2 = (size_t)(col0 >> 5) * M32 + (size_t)row*32 + (col0 & 31);
    *(uint2*)((u16*)Cout + i2) = o;
  } else if (mode == 3) {
    float4 b4 = *(const float4*)(bias + col0);
    uint2 o;
    o.x = cvt_pk(fmaxf(v[0]+b4.x, 0.f), fmaxf(v[1]+b4.y, 0.f));
    o.y = cvt_pk(fmaxf(v[2]+b4.z, 0.f), fmaxf(v[3]+b4.w, 0.f));
    *(uint2*)((u16*)Cout + (size_t)row*N + col0) = o;
  } else if (mode == 7) {
    size_t i2 = (size_t)row*N + col0;
    float4 r4 = *(const float4*)(res + i2);
    float4 b4 = *(const float4*)(bias + col0);
    uint2 o;
    o.x = cvt_pk(v[0]+r4.x+b4.x, v[1]+r4.y+b4.y);
    o.y = cvt_pk(v[2]+r4.z+b4.z, v[3]+r4.w+b4.w);
    *(uint2*)((u16*)Cout + i2) = o;
  } else if (mode == 8) {
    int rr = row >> 7, ss = row & 127;
    size_t i2 = ((size_t)ss*R + rr)*(size_t)N + col0;
    ushort4 r4 = *(const ushort4*)(resb + i2);
    float4 b4 = *(const float4*)(bias + col0);
    uint2 o;
    o.x = cvt_pk(v[0]+bf2f(r4.x)+b4.x, v[1]+bf2f(r4.y)+b4.y);
    o.y = cvt_pk(v[2]+bf2f(r4.z)+b4.z, v[3]+bf2f(r4.w)+b4.w);
    *(uint2*)((u16*)Cout + i2) = o;
  } else if (mode == 9) {
    size_t i2 = (size_t)row*N + col0;
    ushort4 r4 = *(const ushort4*)(resb + i2);
    float4 b4 = *(const float4*)(bias + col0);
    float4 o = make_float4(v[0]+bf2f(r4.x)+b4.x, v[1]+bf2f(r4.y)+b4.y,
                           v[2]+bf2f(r4.z)+b4.z, v[3]+bf2f(r4.w)+b4.w);
    *(float4*)((float*)Cout + i2) = o;
  } else {
    uint2 o; o.x = cvt_pk(v[0], v[1]); o.y = cvt_pk(v[2], v[3]);
    *(uint2*)((u16*)Cout + (size_t)row*N + col0) = o;
  }
}

// ---------------- bf16 MFMA NT GEMM v2: 128x128 tile, 256 thr / 4 waves, BK=32 ----
__global__ __launch_bounds__(256, 4) void gemm_v2(
    const u16* __restrict__ A, const u16* __restrict__ W,
    void* __restrict__ Cout, int N, int K,
    int mode, const float* __restrict__ bias, const float* __restrict__ res)
{
  __shared__ u16 lds[2][2][128*32];
  int t = threadIdx.x, lane = t & 63, wv = t >> 6;
  int g16 = (lane >> 4) & 3, l16 = lane & 15;
  int wm = wv >> 1, wn = wv & 1;

  int gx = gridDim.x;
  int nwg = gx * gridDim.y;
  int p = blockIdx.y * gx + blockIdx.x;
  int cpx = nwg >> 3;
  int lg = (p & 7) * cpx + (p >> 3);
  int bn = (lg % gx) * 128;
  int bm = (lg / gx) * 128;

  int sr = t >> 2;
  int swz8 = ((t & 3) ^ ((sr >> 1) & 3)) << 3;
  int rdch = (g16 ^ ((l16 >> 1) & 3)) << 3;
  int rdoff = l16 * 32 + rdch;

  f32x4 acc[4][4];
  #pragma unroll
  for (int i = 0; i < 4; ++i)
    #pragma unroll
    for (int j = 0; j < 4; ++j) acc[i][j] = (f32x4){0.f,0.f,0.f,0.f};

  const int nkt = K >> 5;

#define STAGE(buf_, kc_) do { \
    gload_lds16(A + (size_t)(bm + sr) * K + (kc_) + swz8, &lds[buf_][0][t*8]); \
    gload_lds16(A + (size_t)(bm + 64 + sr) * K + (kc_) + swz8, &lds[buf_][0][2048 + t*8]); \
    gload_lds16(W + (size_t)(bn + sr) * K + (kc_) + swz8, &lds[buf_][1][t*8]); \
    gload_lds16(W + (size_t)(bn + 64 + sr) * K + (kc_) + swz8, &lds[buf_][1][2048 + t*8]); \
  } while(0)

  STAGE(0, 0);
  for (int kt = 0; kt < nkt; ++kt) {
    if (kt + 1 < nkt) {
      STAGE((kt + 1) & 1, (kt + 1) * 32);
      asm volatile("s_waitcnt vmcnt(4)" ::: "memory");
    } else {
      asm volatile("s_waitcnt vmcnt(0)" ::: "memory");
    }
    __builtin_amdgcn_s_barrier();
    int buf = kt & 1;
    const u16* Abase = &lds[buf][0][wm*2048];
    const u16* Wbase = &lds[buf][1][wn*2048];
    bf16x8 wf[4];
    #pragma unroll
    for (int nf = 0; nf < 4; ++nf)
      wf[nf] = *(const bf16x8*)(Wbase + nf*512 + rdoff);
    __builtin_amdgcn_s_setprio(1);
    #pragma unroll
    for (int mf = 0; mf < 4; ++mf) {
      bf16x8 a0 = *(const bf16x8*)(Abase + mf*512 + rdoff);
      #pragma unroll
      for (int nf = 0; nf < 4; ++nf)
        acc[mf][nf] = __builtin_amdgcn_mfma_f32_16x16x32_bf16(wf[nf], a0, acc[mf][nf], 0, 0, 0);
    }
    __builtin_amdgcn_s_setprio(0);
    asm volatile("" ::: "memory");
    __builtin_amdgcn_s_barrier();
  }
#undef STAGE

  int rowb = bm + wm*64 + l16;
  int colb = bn + wn*64 + (g16 << 2);
  #pragma unroll
  for (int mf = 0; mf < 4; ++mf) {
    int row = rowb + mf*16;
    #pragma unroll
    for (int nf = 0; nf < 4; ++nf)
      epi_store(mode, Cout, N, bias, res, row, colb + nf*16, acc[mf][nf]);
  }
}

// ---- softmax + pack: bias comes pre-packed in fragment order (2x bf16x8) ----
template<bool RM>
__device__ __forceinline__ void softmax_pack(
    const f32x16 &sac, const float* __restrict__ lmbp,
    bf16x8 bf0, bf16x8 bf1, int kb, int hi,
    float &lsum, bf16x8 &pf0, bf16x8 &pf1)
{
  float p[16];
  #pragma unroll
  for (int rq = 0; rq < 4; ++rq) {
    int k0 = kb + 8*rq + 4*hi;
    float4 lm4 = *(const float4*)&lmbp[k0];
    float b0 = lm4.x, b1 = lm4.y, b2 = lm4.z, b3 = lm4.w;
    if (RM) {
      if (rq < 2) {
        b0 += bf2f((u16)bf0[4*rq+0]); b1 += bf2f((u16)bf0[4*rq+1]);
        b2 += bf2f((u16)bf0[4*rq+2]); b3 += bf2f((u16)bf0[4*rq+3]);
      } else {
        b0 += bf2f((u16)bf1[4*rq-8+0]); b1 += bf2f((u16)bf1[4*rq-8+1]);
        b2 += bf2f((u16)bf1[4*rq-8+2]); b3 += bf2f((u16)bf1[4*rq-8+3]);
      }
    }
    p[4*rq+0] = exp2f(sac[4*rq+0] + b0);
    p[4*rq+1] = exp2f(sac[4*rq+1] + b1);
    p[4*rq+2] = exp2f(sac[4*rq+2] + b2);
    p[4*rq+3] = exp2f(sac[4*rq+3] + b3);
    lsum += (p[4*rq+0] + p[4*rq+1]) + (p[4*rq+2] + p[4*rq+3]);
  }
  unsigned u0 = cvt_pk(p[0],  p[1]),  u1 = cvt_pk(p[2],  p[3]);
  unsigned u2 = cvt_pk(p[4],  p[5]),  u3 = cvt_pk(p[6],  p[7]);
  unsigned u4 = cvt_pk(p[8],  p[9]),  u5 = cvt_pk(p[10], p[11]);
  unsigned u6 = cvt_pk(p[12], p[13]), u7 = cvt_pk(p[14], p[15]);
  pl32swap(u0, u2); pl32swap(u1, u3);
  pl32swap(u4, u6); pl32swap(u5, u7);
  pf0 = mk_frag(u0, u1, u2, u3);
  pf1 = mk_frag(u4, u5, u6, u7);
}

// ---------------- MFMA attention, 32x32, 512 thr / 8 waves, head-major QKVG ----
// HPB heads per block; WPH = 8/HPB waves per head; each wave owns 2 q-tiles (64 q).
template<int NKEY, int HPB, bool ROWMODE>
__global__ __launch_bounds__(512, 2) void attn_mfma(
    const u16* __restrict__ QKVG, const u16* __restrict__ biasF,
    const float* __restrict__ mask, u16* __restrict__ og)
{
  __shared__ __align__(16) u16 Vt[HPB][32][NKEY + 8];
  __shared__ float lmb[NKEY];
  constexpr int NKV = NKEY / 32;
  constexpr int WPH = 8 / HPB;
  int b = blockIdx.y;
  int t = threadIdx.x, lane = t & 63, w = t >> 6;
  int c31 = lane & 31, hi = lane >> 5;
  int lh = w / WPH, wtile = w % WPH;
  int hh = blockIdx.x * HPB + lh;

  size_t rbase = (size_t)b * NKEY * 32;
  const u16* Qp = QKVG + (size_t)hh * M32 + rbase;
  const u16* Kp = QKVG + (size_t)(8 + hh) * M32 + rbase;
  const u16* Gp = QKVG + (size_t)(24 + hh) * M32 + rbase;

  for (int i = t; i < HPB*NKEY*4; i += 512) {
    int c0 = (i & 3) * 8;
    int key = (i >> 2) & (NKEY - 1);
    int sh = (i >> 2) / NKEY;
    const u16* Vs = QKVG + (size_t)(16 + blockIdx.x*HPB + sh) * M32 + rbase;
    bf16x8 v8 = *(const bf16x8*)(Vs + (size_t)key*32 + c0);
    #pragma unroll
    for (int j = 0; j < 8; ++j) Vt[sh][c0+j][key] = (u16)v8[j];
  }
  for (int i = t; i < NKEY; i += 512)
    lmb[i] = 1.4426950e9f * ((ROWMODE ? mask[b*R + i] : mask[i*R + b]) - 1.0f);
  __syncthreads();

  int qA = wtile*64 + c31, qB = qA + 32;
  int qtA = wtile*2, qtB = wtile*2 + 1;
  bf16x8 qfA0 = *(const bf16x8*)(Qp + (size_t)qA*32 + hi*8);
  bf16x8 qfA1 = *(const bf16x8*)(Qp + (size_t)qA*32 + 16 + hi*8);
  bf16x8 qfB0 = *(const bf16x8*)(Qp + (size_t)qB*32 + hi*8);
  bf16x8 qfB1 = *(const bf16x8*)(Qp + (size_t)qB*32 + 16 + hi*8);

  f32x16 oA = (f32x16)(0.0f), oB = (f32x16)(0.0f);
  float lsA = 0.f, lsB = 0.f;

#define LOADK(d0_, d1_, g_) do { \
    const u16* kr_ = Kp + ((size_t)((g_)*32) + c31)*32 + hi*8; \
    d0_ = *(const bf16x8*)kr_; d1_ = *(const bf16x8*)(kr_ + 16); \
  } while(0)

#define GROUP_BODY(g_, k0_, k1_) do { \
    int kb_ = (g_) * 32; \
    bf16x8 bA0{}, bA1{}, bB0{}, bB1{}; \
    if (ROWMODE) { \
      const u16* bpA_ = biasF + ((((size_t)hh*8 + (g_))*8 + qtA)*2 + hi)*512 + (size_t)c31*16; \
      bA0 = *(const bf16x8*)bpA_; bA1 = *(const bf16x8*)(bpA_ + 8); \
    } \
    __builtin_amdgcn_s_setprio(1); \
    f32x16 sacA_ = __builtin_amdgcn_mfma_f32_32x32x16_bf16(k0_, qfA0, (f32x16)(0.0f), 0, 0, 0); \
    sacA_ = __builtin_amdgcn_mfma_f32_32x32x16_bf16(k1_, qfA1, sacA_, 0, 0, 0); \
    __builtin_amdgcn_s_setprio(0); \
    bf16x8 va0_ = *(const bf16x8*)&Vt[lh][c31][kb_ + hi*8]; \
    bf16x8 va1_ = *(const bf16x8*)&Vt[lh][c31][kb_ + 16 + hi*8]; \
    bf16x8 pf0_, pf1_; \
    softmax_pack<ROWMODE>(sacA_, lmb, bA0, bA1, kb_, hi, lsA, pf0_, pf1_); \
    __builtin_amdgcn_s_setprio(1); \
    oA = __builtin_amdgcn_mfma_f32_32x32x16_bf16(va0_, pf0_, oA, 0, 0, 0); \
    oA = __builtin_amdgcn_mfma_f32_32x32x16_bf16(va1_, pf1_, oA, 0, 0, 0); \
    __builtin_amdgcn_s_setprio(0); \
    if (ROWMODE) { \
      const u16* bpB_ = biasF + ((((size_t)hh*8 + (g_))*8 + qtB)*2 + hi)*512 + (size_t)c31*16; \
      bB0 = *(const bf16x8*)bpB_; bB1 = *(const bf16x8*)(bpB_ + 8); \
    } \
    __builtin_amdgcn_s_setprio(1); \
    f32x16 sacB_ = __builtin_amdgcn_mfma_f32_32x32x16_bf16(k0_, qfB0, (f32x16)(0.0f), 0, 0, 0); \
    sacB_ = __builtin_amdgcn_mfma_f32_32x32x16_bf16(k1_, qfB1, sacB_, 0, 0, 0); \
    __builtin_amdgcn_s_setprio(0); \
    softmax_pack<ROWMODE>(sacB_, lmb, bB0, bB1, kb_, hi, lsB, pf0_, pf1_); \
    __builtin_amdgcn_s_setprio(1); \
    oB = __builtin_amdgcn_mfma_f32_32x32x16_bf16(va0_, pf0_, oB, 0, 0, 0); \
    oB = __builtin_amdgcn_mfma_f32_32x32x16_bf16(va1_, pf1_, oB, 0, 0, 0); \
    __builtin_amdgcn_s_setprio(0); \
  } while(0)

  bf16x8 ke0{}, ke1{}, ko0{}, ko1{};
  LOADK(ke0, ke1, 0);
  LOADK(ko0, ko1, 1);
  for (int g = 0; g < NKV; g += 2) {
    bf16x8 c0 = ke0, c1 = ke1;
    if (g + 2 < NKV) LOADK(ke0, ke1, g + 2);
    GROUP_BODY(g, c0, c1);
    bf16x8 d0 = ko0, d1 = ko1;
    if (g + 3 < NKV) LOADK(ko0, ko1, g + 3);
    GROUP_BODY(g + 1, d0, d1);
  }
#undef GROUP_BODY
#undef LOADK

  lsA += __shfl_xor(lsA, 32);
  lsB += __shfl_xor(lsB, 32);
  float invA = 1.0f / lsA, invB = 1.0f / lsB;

  size_t baseO = (size_t)b * NKEY * 256 + (size_t)hh * 32;
  #pragma unroll
  for (int tile = 0; tile < 2; ++tile) {
    int q = (tile == 0) ? qA : qB;
    float inv = (tile == 0) ? invA : invB;
    const f32x16 &oo = (tile == 0) ? oA : oB;
    u16* op = og + baseO + (size_t)q * 256;
    const u16* gp = Gp + (size_t)q * 32;
    #pragma unroll
    for (int rq = 0; rq < 4; ++rq) {
      int c0 = 8*rq + 4*hi;
      ushort4 g4 = *(const ushort4*)(gp + c0);
      float f0 = oo[4*rq+0] * inv * bf2f(g4.x);
      float f1 = oo[4*rq+1] * inv * bf2f(g4.y);
      float f2 = oo[4*rq+2] * inv * bf2f(g4.z);
      float f3 = oo[4*rq+3] * inv * bf2f(g4.w);
      uint2 o2; o2.x = cvt_pk(f0, f1); o2.y = cvt_pk(f2, f3);
      *(uint2*)(op + c0) = o2;
    }
  }
}

extern "C" void kernel_launch(void* const* d_in, const int* in_sizes, int n_in,
                              void* d_out, int out_size, void* d_ws, size_t ws_size,
                              hipStream_t stream)
{
  const float* node         = (const float*)d_in[0];
  const float* pair         = (const float*)d_in[1];
  const float* node_mask    = (const float*)d_in[2];
  const float* row_ln_m_g   = (const float*)d_in[3];
  const float* row_ln_m_b   = (const float*)d_in[4];
  const float* row_ln_z_g   = (const float*)d_in[5];
  const float* row_ln_z_b   = (const float*)d_in[6];
  const float* row_b_w      = (const float*)d_in[7];
  const float* row_wq       = (const float*)d_in[8];
  const float* row_wk       = (const float*)d_in[9];
  const float* row_wv       = (const float*)d_in[10];
  const float* row_wg       = (const float*)d_in[11];
  const float* row_bg       = (const float*)d_in[12];
  const float* row_wo       = (const float*)d_in[13];
  const float* row_out_bias = (const float*)d_in[14];
  const float* col_ln_g     = (const float*)d_in[15];
  const float* col_ln_b     = (const float*)d_in[16];
  const float* col_wq       = (const float*)d_in[17];
  const float* col_wk       = (const float*)d_in[18];
  const float* col_wv       = (const float*)d_in[19];
  const float* col_wg       = (const float*)d_in[20];
  const float* col_bg       = (const float*)d_in[21];
  const float* col_wo       = (const float*)d_in[22];
  const float* col_bo       = (const float*)d_in[23];
  const float* tr_ln_g      = (const float*)d_in[24];
  const float* tr_ln_b      = (const float*)d_in[25];
  const float* tr_w1        = (const float*)d_in[26];
  const float* tr_b1        = (const float*)d_in[27];
  const float* tr_w2        = (const float*)d_in[28];
  const float* tr_b2        = (const float*)d_in[29];

  float* out = (float*)d_out;
  char* ws8 = (char*)d_ws;
  const size_t MB = 1ull << 20;
  u16*   A     = (u16*)(ws8);               // 16 MB  LN out [32768][256] bf16
  u16*   QKVG  = (u16*)(ws8 + 16*MB);       // 64 MB  head-major 32 x [32768][32] (also T1)
  u16*   Ob    = (u16*)(ws8 + 80*MB);       // 16 MB  gated attn out bf16 [row][256]
  u16*   DbF   = (u16*)(ws8 + 96*MB);       // 4 MB   bias fragments
  u16*   N1    = (u16*)(ws8 + 100*MB);      // 16 MB  node1 bf16 [s][r][256]
  u16*   N2    = (u16*)(ws8 + 116*MB);      // 16 MB  node2 bf16 [s][r][256]
  u16*   Wb    = (u16*)(ws8 + 132*MB);      // bf16 weight arena
  u16*   T1    = QKVG;

  const float qs = 0.17677669529663687f;    // 1/sqrt(32)

  u16* Wrqkvg = Wb + 0;
  u16* Wro    = Wb + 262144;
  u16* Wcqkvg = Wb + 327680;
  u16* Wco    = Wb + 589824;
  u16* W1w    = Wb + 655360;
  u16* W2w    = Wb + 917504;

  CvtArgs ca;
  const float* srcs[12] = {row_wq,row_wk,row_wv,row_wg,row_wo,
                           col_wq,col_wk,col_wv,col_wg,col_wo,tr_w1,tr_w2};
  int offs[12] = {0,65536,131072,196608,262144,327680,393216,458752,524288,589824,655360,917504};
  int ns[12]   = {65536,65536,65536,65536,65536,65536,65536,65536,65536,65536,262144,262144};
  for (int i = 0; i < 12; ++i) {
    ca.src[i] = srcs[i]; ca.off[i] = offs[i]; ca.n[i] = ns[i];
    ca.scale[i] = (i == 0 || i == 5) ? qs * LOG2E : 1.0f;
  }
  cvt_w_kernel<<<dim3(256,12), 256, 0, stream>>>(ca, Wb);

  dim3 g1024(8, 256);   // 128x128 tiles, N=1024 -> 2048 blocks
  dim3 g256(2, 256);    // 128x128 tiles, N=256  -> 512 blocks

  // --- row attention ---
  ln256_kernel<<<8192, 256, 0, stream>>>(node, A, row_ln_m_g, row_ln_m_b, 0, 0);
  pair_bias_kernel<<<4096, 256, 0, stream>>>(pair, row_ln_z_g, row_ln_z_b, row_b_w, DbF);
  gemm_v2<<<g1024, 256, 0, stream>>>(A, Wrqkvg, QKVG, 1024, 256, 6, row_bg, nullptr);
  attn_mfma<256,2,true><<<dim3(4,128), 512, 0, stream>>>(QKVG, DbF, node_mask, Ob);
  gemm_v2<<<g256, 256, 0, stream>>>(Ob, Wro, N1, 256, 256, 7, row_out_bias, node);

  // --- column attention (in [r,s,d] layout) ---
  ln256_kernel<<<8192, 256, 0, stream>>>(N1, A, col_ln_g, col_ln_b, 1, 1);
  gemm_v2<<<g1024, 256, 0, stream>>>(A, Wcqkvg, QKVG, 1024, 256, 6, col_bg, nullptr);
  attn_mfma<128,4,false><<<dim3(2,256), 512, 0, stream>>>(QKVG, nullptr, node_mask, Ob);
  gemm_v2<<<g256, 256, 0, stream>>>(Ob, Wco, N2, 256, 256, 8, col_bo, (const float*)N1);

  // --- transition ---
  ln256_kernel<<<8192, 256, 0, stream>>>(N2, A, tr_ln_g, tr_ln_b, 0, 1);
  gemm_v2<<<g1024, 256, 0, stream>>>(A, W1w, T1, 1024, 256, 3, tr_b1, nullptr);
  gemm_v2<<<g256, 256, 0, stream>>>(T1, W2w, out, 256, 1024, 9, tr_b2, (const float*)N2);
}

// Round 22
// 284.094 us; speedup vs baseline: 1.1138x; 1.0077x over previous
//
#include <hip/hip_runtime.h>
#include <math.h>

#define S 128
#define R 256
#define DMODEL 256
#define H 8
#define CDIM 32
#define HC 256
#define DFF 1024
#define NROWS (S*R)     // 32768
#define NPAIR (R*R)     // 65536
#define LN_EPS 1e-5f
#define LOG2E 1.4426950408889634f
#define M32 ((size_t)NROWS * 32)

typedef unsigned short u16;
typedef __attribute__((ext_vector_type(8))) short bf16x8;
typedef __attribute__((ext_vector_type(4))) float f32x4;
typedef __attribute__((ext_vector_type(16))) float f32x16;

__device__ __forceinline__ u16 f2bf(float x) {
  unsigned u = __float_as_uint(x);
  u = (u + 0x7fffu + ((u >> 16) & 1u)) >> 16;
  return (u16)u;
}
__device__ __forceinline__ float bf2f(u16 x) {
  return __uint_as_float(((unsigned)x) << 16);
}
__device__ __forceinline__ unsigned cvt_pk(float a, float b) {
  unsigned r;
  asm("v_cvt_pk_bf16_f32 %0, %1, %2" : "=v"(r) : "v"(a), "v"(b));
  return r;
}
__device__ __forceinline__ void pl32swap(unsigned &a, unsigned &b) {
  asm("v_permlane32_swap_b32 %0, %1" : "+v"(a), "+v"(b));
}
__device__ __forceinline__ bf16x8 mk_frag(unsigned a, unsigned b, unsigned c, unsigned d) {
  uint4 t = make_uint4(a, b, c, d);
  return __builtin_bit_cast(bf16x8, t);
}

__device__ __forceinline__ void gload_lds16(const u16* g, u16* l) {
  __builtin_amdgcn_global_load_lds(
      (const __attribute__((address_space(1))) unsigned int*)g,
      (__attribute__((address_space(3))) unsigned int*)l, 16, 0, 0);
}

// ---------------- weight f32 -> bf16 conversion (12 segments) ----------------
struct CvtArgs {
  const float* src[12];
  int off[12];
  int n[12];
  float scale[12];
};

__global__ __launch_bounds__(256) void cvt_w_kernel(CvtArgs a, u16* __restrict__ dst) {
  int sg = blockIdx.y;
  int i = (blockIdx.x * 256 + threadIdx.x) * 4;
  if (i >= a.n[sg]) return;
  float4 v = *(const float4*)(a.src[sg] + i);
  float sc = a.scale[sg];
  uint2 o;
  o.x = cvt_pk(v.x * sc, v.y * sc);
  o.y = cvt_pk(v.z * sc, v.w * sc);
  *(uint2*)(dst + a.off[sg] + i) = o;
}

// ---------------- LayerNorm over 256, one row per wave, bf16 out ----------------
__global__ __launch_bounds__(256) void ln256_kernel(
    const void* __restrict__ in, u16* __restrict__ out,
    const float* __restrict__ gamma, const float* __restrict__ beta,
    int tmode, int inbf)
{
  int wid = threadIdx.x >> 6, lane = threadIdx.x & 63;
  int m = blockIdx.x * 4 + wid;
  int inrow = m;
  if (tmode) { int r = m >> 7, s = m & 127; inrow = s * R + r; }
  float4 x;
  if (inbf) {
    ushort4 u = *(const ushort4*)((const u16*)in + (size_t)inrow * DMODEL + lane * 4);
    x.x = bf2f(u.x); x.y = bf2f(u.y); x.z = bf2f(u.z); x.w = bf2f(u.w);
  } else {
    x = *(const float4*)((const float*)in + (size_t)inrow * DMODEL + lane * 4);
  }
  float sum = x.x + x.y + x.z + x.w;
  float sq  = x.x*x.x + x.y*x.y + x.z*x.z + x.w*x.w;
  #pragma unroll
  for (int off = 32; off; off >>= 1) {
    sum += __shfl_xor(sum, off);
    sq  += __shfl_xor(sq, off);
  }
  float mean = sum * (1.0f/256.0f);
  float var  = sq  * (1.0f/256.0f) - mean*mean;
  float rstd = rsqrtf(var + LN_EPS);
  float4 g = *(const float4*)(gamma + lane*4);
  float4 b = *(const float4*)(beta  + lane*4);
  uint2 o;
  o.x = cvt_pk((x.x-mean)*rstd*g.x + b.x, (x.y-mean)*rstd*g.y + b.y);
  o.y = cvt_pk((x.z-mean)*rstd*g.z + b.z, (x.w-mean)*rstd*g.w + b.w);
  *(uint2*)(out + (size_t)m * DMODEL + lane*4) = o;
}

// -- pair LN (over 128) + bias projection -> FRAGMENT layout bias (bf16, *log2e) --
__global__ __launch_bounds__(256) void pair_bias_kernel(
    const float* __restrict__ pair, const float* __restrict__ gamma,
    const float* __restrict__ beta, const float* __restrict__ bw,
    u16* __restrict__ bias)
{
  int t = threadIdx.x;
  int lane = t & 63, wv = t >> 6;
  int sub = lane >> 4, l16 = lane & 15;
  int p = blockIdx.x * 16 + wv * 4 + sub;    // row index = q*256 + k
  const float* xp = pair + (size_t)p * 128 + l16 * 8;
  float4 x0 = *(const float4*)xp;
  float4 x1 = *(const float4*)(xp + 4);
  float xs[8] = {x0.x, x0.y, x0.z, x0.w, x1.x, x1.y, x1.z, x1.w};

  float sum = 0.f, sq = 0.f;
  #pragma unroll
  for (int j = 0; j < 8; ++j) { sum += xs[j]; sq += xs[j]*xs[j]; }
  #pragma unroll
  for (int d = 1; d < 16; d <<= 1) {
    sum += __shfl_xor(sum, d);
    sq  += __shfl_xor(sq, d);
  }
  float mean = sum * (1.0f/128.0f);
  float rstd = rsqrtf(sq*(1.0f/128.0f) - mean*mean + LN_EPS);

  const float* gp = gamma + l16*8;
  const float* bp = beta  + l16*8;
  float4 g0 = *(const float4*)gp, g1 = *(const float4*)(gp + 4);
  float4 b0 = *(const float4*)bp, b1 = *(const float4*)(bp + 4);
  float gg[8] = {g0.x,g0.y,g0.z,g0.w,g1.x,g1.y,g1.z,g1.w};
  float bb[8] = {b0.x,b0.y,b0.z,b0.w,b1.x,b1.y,b1.z,b1.w};
  float z[8];
  #pragma unroll
  for (int j = 0; j < 8; ++j) z[j] = (xs[j]-mean)*rstd*gg[j] + bb[j];

  float a[8];
  #pragma unroll
  for (int h = 0; h < 8; ++h) {
    const float* wp = bw + h*128 + l16*8;
    float4 w0 = *(const float4*)wp, w1 = *(const float4*)(wp + 4);
    a[h] = z[0]*w0.x + z[1]*w0.y + z[2]*w0.z + z[3]*w0.w
         + z[4]*w1.x + z[5]*w1.y + z[6]*w1.z + z[7]*w1.w;
  }

  #pragma unroll
  for (int i = 0; i < 4; ++i) {
    float send = (lane & 1) ? a[i] : a[i+4];
    float recv = __shfl_xor(send, 1);
    a[i] = ((lane & 1) ? a[i+4] : a[i]) + recv;
  }
  #pragma unroll
  for (int i = 0; i < 2; ++i) {
    float send = (lane & 2) ? a[i] : a[i+2];
    float recv = __shfl_xor(send, 2);
    a[i] = ((lane & 2) ? a[i+2] : a[i]) + recv;
  }
  {
    float send = (lane & 4) ? a[0] : a[1];
    float recv = __shfl_xor(send, 4);
    a[0] = ((lane & 4) ? a[1] : a[0]) + recv;
  }
  a[0] += __shfl_xor(a[0], 8);
  int h = 4*(l16 & 1) + (l16 & 2) + ((l16 >> 2) & 1);

  if (l16 < 8) {
    int q = p >> 8, k = p & 255;
    int kt = k >> 5, qt = q >> 5, c31 = q & 31;
    int kk = k & 31;
    int hi2 = (kk >> 2) & 1;
    int j = (kk & 3) | ((kk >> 3) << 2);
    size_t addr = ((((size_t)h*8 + kt)*8 + qt)*2 + hi2)*512 + (size_t)c31*16 + j;
    bias[addr] = f2bf(a[0] * LOG2E);
  }
}

// ---------- shared epilogue for one (row, col0, f32x4) output quad ----------
__device__ __forceinline__ void epi_store(
    int mode, void* __restrict__ Cout, int N,
    const float* __restrict__ bias, const float* __restrict__ res,
    int row, int col0, f32x4 v)
{
  const u16* resb = (const u16*)res;
  if (mode == 6) {
    if (col0 >= 768) {
      float4 b4 = *(const float4*)(bias + col0 - 768);
      v[0] = 1.0f/(1.0f+__expf(-(v[0]+b4.x)));
      v[1] = 1.0f/(1.0f+__expf(-(v[1]+b4.y)));
      v[2] = 1.0f/(1.0f+__expf(-(v[2]+b4.z)));
      v[3] = 1.0f/(1.0f+__expf(-(v[3]+b4.w)));
    }
    uint2 o; o.x = cvt_pk(v[0], v[1]); o.y = cvt_pk(v[2], v[3]);
    size_t i2 = (size_t)(col0 >> 5) * M32 + (size_t)row*32 + (col0 & 31);
    *(uint2*)((u16*)Cout + i2) = o;
  } else if (mode == 3) {
    float4 b4 = *(const float4*)(bias + col0);
    uint2 o;
    o.x = cvt_pk(fmaxf(v[0]+b4.x, 0.f), fmaxf(v[1]+b4.y, 0.f));
    o.y = cvt_pk(fmaxf(v[2]+b4.z, 0.f), fmaxf(v[3]+b4.w, 0.f));
    *(uint2*)((u16*)Cout + (size_t)row*N + col0) = o;
  } else if (mode == 7) {
    size_t i2 = (size_t)row*N + col0;
    float4 r4 = *(const float4*)(res + i2);
    float4 b4 = *(const float4*)(bias + col0);
    uint2 o;
    o.x = cvt_pk(v[0]+r4.x+b4.x, v[1]+r4.y+b4.y);
    o.y = cvt_pk(v[2]+r4.z+b4.z, v[3]+r4.w+b4.w);
    *(uint2*)((u16*)Cout + i2) = o;
  } else if (mode == 8) {
    int rr = row >> 7, ss = row & 127;
    size_t i2 = ((size_t)ss*R + rr)*(size_t)N + col0;
    ushort4 r4 = *(const ushort4*)(resb + i2);
    float4 b4 = *(const float4*)(bias + col0);
    uint2 o;
    o.x = cvt_pk(v[0]+bf2f(r4.x)+b4.x, v[1]+bf2f(r4.y)+b4.y);
    o.y = cvt_pk(v[2]+bf2f(r4.z)+b4.z, v[3]+bf2f(r4.w)+b4.w);
    *(uint2*)((u16*)Cout + i2) = o;
  } else if (mode == 9) {
    size_t i2 = (size_t)row*N + col0;
    ushort4 r4 = *(const ushort4*)(resb + i2);
    float4 b4 = *(const float4*)(bias + col0);
    float4 o = make_float4(v[0]+bf2f(r4.x)+b4.x, v[1]+bf2f(r4.y)+b4.y,
                           v[2]+bf2f(r4.z)+b4.z, v[3]+bf2f(r4.w)+b4.w);
    *(float4*)((float*)Cout + i2) = o;
  } else {
    uint2 o; o.x = cvt_pk(v[0], v[1]); o.y = cvt_pk(v[2], v[3]);
    *(uint2*)((u16*)Cout + (size_t)row*N + col0) = o;
  }
}

// ---------------- bf16 MFMA NT GEMM v2: 128x128 tile, 256 thr / 4 waves, BK=32 ----
__global__ __launch_bounds__(256, 4) void gemm_v2(
    const u16* __restrict__ A, const u16* __restrict__ W,
    void* __restrict__ Cout, int N, int K,
    int mode, const float* __restrict__ bias, const float* __restrict__ res)
{
  __shared__ u16 lds[2][2][128*32];
  int t = threadIdx.x, lane = t & 63, wv = t >> 6;
  int g16 = (lane >> 4) & 3, l16 = lane & 15;
  int wm = wv >> 1, wn = wv & 1;

  int gx = gridDim.x;
  int nwg = gx * gridDim.y;
  int p = blockIdx.y * gx + blockIdx.x;
  int cpx = nwg >> 3;
  int lg = (p & 7) * cpx + (p >> 3);
  int bn = (lg % gx) * 128;
  int bm = (lg / gx) * 128;

  int sr = t >> 2;
  int swz8 = ((t & 3) ^ ((sr >> 1) & 3)) << 3;
  int rdch = (g16 ^ ((l16 >> 1) & 3)) << 3;
  int rdoff = l16 * 32 + rdch;

  f32x4 acc[4][4];
  #pragma unroll
  for (int i = 0; i < 4; ++i)
    #pragma unroll
    for (int j = 0; j < 4; ++j) acc[i][j] = (f32x4){0.f,0.f,0.f,0.f};

  const int nkt = K >> 5;

#define STAGE(buf_, kc_) do { \
    gload_lds16(A + (size_t)(bm + sr) * K + (kc_) + swz8, &lds[buf_][0][t*8]); \
    gload_lds16(A + (size_t)(bm + 64 + sr) * K + (kc_) + swz8, &lds[buf_][0][2048 + t*8]); \
    gload_lds16(W + (size_t)(bn + sr) * K + (kc_) + swz8, &lds[buf_][1][t*8]); \
    gload_lds16(W + (size_t)(bn + 64 + sr) * K + (kc_) + swz8, &lds[buf_][1][2048 + t*8]); \
  } while(0)

  STAGE(0, 0);
  for (int kt = 0; kt < nkt; ++kt) {
    if (kt + 1 < nkt) {
      STAGE((kt + 1) & 1, (kt + 1) * 32);
      asm volatile("s_waitcnt vmcnt(4)" ::: "memory");
    } else {
      asm volatile("s_waitcnt vmcnt(0)" ::: "memory");
    }
    __builtin_amdgcn_s_barrier();
    int buf = kt & 1;
    const u16* Abase = &lds[buf][0][wm*2048];
    const u16* Wbase = &lds[buf][1][wn*2048];
    bf16x8 wf[4];
    #pragma unroll
    for (int nf = 0; nf < 4; ++nf)
      wf[nf] = *(const bf16x8*)(Wbase + nf*512 + rdoff);
    __builtin_amdgcn_s_setprio(1);
    #pragma unroll
    for (int mf = 0; mf < 4; ++mf) {
      bf16x8 a0 = *(const bf16x8*)(Abase + mf*512 + rdoff);
      #pragma unroll
      for (int nf = 0; nf < 4; ++nf)
        acc[mf][nf] = __builtin_amdgcn_mfma_f32_16x16x32_bf16(wf[nf], a0, acc[mf][nf], 0, 0, 0);
    }
    __builtin_amdgcn_s_setprio(0);
    asm volatile("" ::: "memory");
    __builtin_amdgcn_s_barrier();
  }
#undef STAGE

  int rowb = bm + wm*64 + l16;
  int colb = bn + wn*64 + (g16 << 2);
  #pragma unroll
  for (int mf = 0; mf < 4; ++mf) {
    int row = rowb + mf*16;
    #pragma unroll
    for (int nf = 0; nf < 4; ++nf)
      epi_store(mode, Cout, N, bias, res, row, colb + nf*16, acc[mf][nf]);
  }
}

// ---- softmax + pack: bias comes pre-packed in fragment order (2x bf16x8) ----
template<bool RM>
__device__ __forceinline__ void softmax_pack(
    const f32x16 &sac, const float* __restrict__ lmbp,
    bf16x8 bf0, bf16x8 bf1, int kb, int hi,
    float &lsum, bf16x8 &pf0, bf16x8 &pf1)
{
  float p[16];
  #pragma unroll
  for (int rq = 0; rq < 4; ++rq) {
    int k0 = kb + 8*rq + 4*hi;
    float4 lm4 = *(const float4*)&lmbp[k0];
    float b0 = lm4.x, b1 = lm4.y, b2 = lm4.z, b3 = lm4.w;
    if (RM) {
      if (rq < 2) {
        b0 += bf2f((u16)bf0[4*rq+0]); b1 += bf2f((u16)bf0[4*rq+1]);
        b2 += bf2f((u16)bf0[4*rq+2]); b3 += bf2f((u16)bf0[4*rq+3]);
      } else {
        b0 += bf2f((u16)bf1[4*rq-8+0]); b1 += bf2f((u16)bf1[4*rq-8+1]);
        b2 += bf2f((u16)bf1[4*rq-8+2]); b3 += bf2f((u16)bf1[4*rq-8+3]);
      }
    }
    p[4*rq+0] = exp2f(sac[4*rq+0] + b0);
    p[4*rq+1] = exp2f(sac[4*rq+1] + b1);
    p[4*rq+2] = exp2f(sac[4*rq+2] + b2);
    p[4*rq+3] = exp2f(sac[4*rq+3] + b3);
    lsum += (p[4*rq+0] + p[4*rq+1]) + (p[4*rq+2] + p[4*rq+3]);
  }
  unsigned u0 = cvt_pk(p[0],  p[1]),  u1 = cvt_pk(p[2],  p[3]);
  unsigned u2 = cvt_pk(p[4],  p[5]),  u3 = cvt_pk(p[6],  p[7]);
  unsigned u4 = cvt_pk(p[8],  p[9]),  u5 = cvt_pk(p[10], p[11]);
  unsigned u6 = cvt_pk(p[12], p[13]), u7 = cvt_pk(p[14], p[15]);
  pl32swap(u0, u2); pl32swap(u1, u3);
  pl32swap(u4, u6); pl32swap(u5, u7);
  pf0 = mk_frag(u0, u1, u2, u3);
  pf1 = mk_frag(u4, u5, u6, u7);
}

// ---------------- MFMA attention, 32x32, 512 thr / 8 waves, q-range split ----
// HPB heads per block; WPH = 8/HPB waves per head; each wave owns ONE q-tile (32 q).
// QSPLIT q-range splits -> grid (H/HPB, B*QSPLIT); blocks = 1024 for both attns.
// Write spans per block unchanged vs R18 (row 64B, col 128B).
template<int NKEY, int HPB, int QSPLIT, bool ROWMODE>
__global__ __launch_bounds__(512, 2) void attn_mfma(
    const u16* __restrict__ QKVG, const u16* __restrict__ biasF,
    const float* __restrict__ mask, u16* __restrict__ og)
{
  __shared__ __align__(16) u16 Vt[HPB][32][NKEY + 8];
  __shared__ float lmb[NKEY];
  constexpr int NKV = NKEY / 32;
  constexpr int WPH = 8 / HPB;
  int b = blockIdx.y / QSPLIT;
  int qh = blockIdx.y % QSPLIT;
  int t = threadIdx.x, lane = t & 63, w = t >> 6;
  int c31 = lane & 31, hi = lane >> 5;
  int lh = w / WPH, wtile = w % WPH;
  int hh = blockIdx.x * HPB + lh;

  size_t rbase = (size_t)b * NKEY * 32;
  const u16* Qp = QKVG + (size_t)hh * M32 + rbase;
  const u16* Kp = QKVG + (size_t)(8 + hh) * M32 + rbase;
  const u16* Gp = QKVG + (size_t)(24 + hh) * M32 + rbase;

  for (int i = t; i < HPB*NKEY*4; i += 512) {
    int c0 = (i & 3) * 8;
    int key = (i >> 2) & (NKEY - 1);
    int sh = (i >> 2) / NKEY;
    const u16* Vs = QKVG + (size_t)(16 + blockIdx.x*HPB + sh) * M32 + rbase;
    bf16x8 v8 = *(const bf16x8*)(Vs + (size_t)key*32 + c0);
    #pragma unroll
    for (int j = 0; j < 8; ++j) Vt[sh][c0+j][key] = (u16)v8[j];
  }
  for (int i = t; i < NKEY; i += 512)
    lmb[i] = 1.4426950e9f * ((ROWMODE ? mask[b*R + i] : mask[i*R + b]) - 1.0f);
  __syncthreads();

  int qA = qh*(WPH*32) + wtile*32 + c31;
  int qtA = qh*WPH + wtile;
  bf16x8 qfA0 = *(const bf16x8*)(Qp + (size_t)qA*32 + hi*8);
  bf16x8 qfA1 = *(const bf16x8*)(Qp + (size_t)qA*32 + 16 + hi*8);

  f32x16 oA = (f32x16)(0.0f);
  float lsA = 0.f;

#define LOADK(d0_, d1_, g_) do { \
    const u16* kr_ = Kp + ((size_t)((g_)*32) + c31)*32 + hi*8; \
    d0_ = *(const bf16x8*)kr_; d1_ = *(const bf16x8*)(kr_ + 16); \
  } while(0)

#define GROUP_BODY(g_, k0_, k1_) do { \
    int kb_ = (g_) * 32; \
    bf16x8 bA0{}, bA1{}; \
    if (ROWMODE) { \
      const u16* bpA_ = biasF + ((((size_t)hh*8 + (g_))*8 + qtA)*2 + hi)*512 + (size_t)c31*16; \
      bA0 = *(const bf16x8*)bpA_; bA1 = *(const bf16x8*)(bpA_ + 8); \
    } \
    __builtin_amdgcn_s_setprio(1); \
    f32x16 sacA_ = __builtin_amdgcn_mfma_f32_32x32x16_bf16(k0_, qfA0, (f32x16)(0.0f), 0, 0, 0); \
    sacA_ = __builtin_amdgcn_mfma_f32_32x32x16_bf16(k1_, qfA1, sacA_, 0, 0, 0); \
    __builtin_amdgcn_s_setprio(0); \
    bf16x8 va0_ = *(const bf16x8*)&Vt[lh][c31][kb_ + hi*8]; \
    bf16x8 va1_ = *(const bf16x8*)&Vt[lh][c31][kb_ + 16 + hi*8]; \
    bf16x8 pf0_, pf1_; \
    softmax_pack<ROWMODE>(sacA_, lmb, bA0, bA1, kb_, hi, lsA, pf0_, pf1_); \
    __builtin_amdgcn_s_setprio(1); \
    oA = __builtin_amdgcn_mfma_f32_32x32x16_bf16(va0_, pf0_, oA, 0, 0, 0); \
    oA = __builtin_amdgcn_mfma_f32_32x32x16_bf16(va1_, pf1_, oA, 0, 0, 0); \
    __builtin_amdgcn_s_setprio(0); \
  } while(0)

  bf16x8 ke0{}, ke1{}, ko0{}, ko1{};
  LOADK(ke0, ke1, 0);
  if (NKV > 1) LOADK(ko0, ko1, 1);
  for (int g = 0; g < NKV; g += 2) {
    bf16x8 c0 = ke0, c1 = ke1;
    if (g + 2 < NKV) LOADK(ke0, ke1, g + 2);
    GROUP_BODY(g, c0, c1);
    bf16x8 d0 = ko0, d1 = ko1;
    if (g + 3 < NKV) LOADK(ko0, ko1, g + 3);
    GROUP_BODY(g + 1, d0, d1);
  }
#undef GROUP_BODY
#undef LOADK

  lsA += __shfl_xor(lsA, 32);
  float invA = 1.0f / lsA;

  size_t baseO = (size_t)b * NKEY * 256 + (size_t)hh * 32;
  {
    u16* op = og + baseO + (size_t)qA * 256;
    const u16* gp = Gp + (size_t)qA * 32;
    #pragma unroll
    for (int rq = 0; rq < 4; ++rq) {
      int c0 = 8*rq + 4*hi;
      ushort4 g4 = *(const ushort4*)(gp + c0);
      float f0 = oA[4*rq+0] * invA * bf2f(g4.x);
      float f1 = oA[4*rq+1] * invA * bf2f(g4.y);
      float f2 = oA[4*rq+2] * invA * bf2f(g4.z);
      float f3 = oA[4*rq+3] * invA * bf2f(g4.w);
      uint2 o2; o2.x = cvt_pk(f0, f1); o2.y = cvt_pk(f2, f3);
      *(uint2*)(op + c0) = o2;
    }
  }
}

extern "C" void kernel_launch(void* const* d_in, const int* in_sizes, int n_in,
                              void* d_out, int out_size, void* d_ws, size_t ws_size,
                              hipStream_t stream)
{
  const float* node         = (const float*)d_in[0];
  const float* pair         = (const float*)d_in[1];
  const float* node_mask    = (const float*)d_in[2];
  const float* row_ln_m_g   = (const float*)d_in[3];
  const float* row_ln_m_b   = (const float*)d_in[4];
  const float* row_ln_z_g   = (const float*)d_in[5];
  const float* row_ln_z_b   = (const float*)d_in[6];
  const float* row_b_w      = (const float*)d_in[7];
  const float* row_wq       = (const float*)d_in[8];
  const float* row_wk       = (const float*)d_in[9];
  const float* row_wv       = (const float*)d_in[10];
  const float* row_wg       = (const float*)d_in[11];
  const float* row_bg       = (const float*)d_in[12];
  const float* row_wo       = (const float*)d_in[13];
  const float* row_out_bias = (const float*)d_in[14];
  const float* col_ln_g     = (const float*)d_in[15];
  const float* col_ln_b     = (const float*)d_in[16];
  const float* col_wq       = (const float*)d_in[17];
  const float* col_wk       = (const float*)d_in[18];
  const float* col_wv       = (const float*)d_in[19];
  const float* col_wg       = (const float*)d_in[20];
  const float* col_bg       = (const float*)d_in[21];
  const float* col_wo       = (const float*)d_in[22];
  const float* col_bo       = (const float*)d_in[23];
  const float* tr_ln_g      = (const float*)d_in[24];
  const float* tr_ln_b      = (const float*)d_in[25];
  const float* tr_w1        = (const float*)d_in[26];
  const float* tr_b1        = (const float*)d_in[27];
  const float* tr_w2        = (const float*)d_in[28];
  const float* tr_b2        = (const float*)d_in[29];

  float* out = (float*)d_out;
  char* ws8 = (char*)d_ws;
  const size_t MB = 1ull << 20;
  u16*   A     = (u16*)(ws8);               // 16 MB  LN out [32768][256] bf16
  u16*   QKVG  = (u16*)(ws8 + 16*MB);       // 64 MB  head-major 32 x [32768][32] (also T1)
  u16*   Ob    = (u16*)(ws8 + 80*MB);       // 16 MB  gated attn out bf16 [row][256]
  u16*   DbF   = (u16*)(ws8 + 96*MB);       // 4 MB   bias fragments
  u16*   N1    = (u16*)(ws8 + 100*MB);      // 16 MB  node1 bf16 [s][r][256]
  u16*   N2    = (u16*)(ws8 + 116*MB);      // 16 MB  node2 bf16 [s][r][256]
  u16*   Wb    = (u16*)(ws8 + 132*MB);      // bf16 weight arena
  u16*   T1    = QKVG;

  const float qs = 0.17677669529663687f;    // 1/sqrt(32)

  u16* Wrqkvg = Wb + 0;
  u16* Wro    = Wb + 262144;
  u16* Wcqkvg = Wb + 327680;
  u16* Wco    = Wb + 589824;
  u16* W1w    = Wb + 655360;
  u16* W2w    = Wb + 917504;

  CvtArgs ca;
  const float* srcs[12] = {row_wq,row_wk,row_wv,row_wg,row_wo,
                           col_wq,col_wk,col_wv,col_wg,col_wo,tr_w1,tr_w2};
  int offs[12] = {0,65536,131072,196608,262144,327680,393216,458752,524288,589824,655360,917504};
  int ns[12]   = {65536,65536,65536,65536,65536,65536,65536,65536,65536,65536,262144,262144};
  for (int i = 0; i < 12; ++i) {
    ca.src[i] = srcs[i]; ca.off[i] = offs[i]; ca.n[i] = ns[i];
    ca.scale[i] = (i == 0 || i == 5) ? qs * LOG2E : 1.0f;
  }
  cvt_w_kernel<<<dim3(256,12), 256, 0, stream>>>(ca, Wb);

  dim3 g1024(8, 256);   // 128x128 tiles, N=1024 -> 2048 blocks
  dim3 g256(2, 256);    // 128x128 tiles, N=256  -> 512 blocks

  // --- row attention ---
  ln256_kernel<<<8192, 256, 0, stream>>>(node, A, row_ln_m_g, row_ln_m_b, 0, 0);
  pair_bias_kernel<<<4096, 256, 0, stream>>>(pair, row_ln_z_g, row_ln_z_b, row_b_w, DbF);
  gemm_v2<<<g1024, 256, 0, stream>>>(A, Wrqkvg, QKVG, 1024, 256, 6, row_bg, nullptr);
  attn_mfma<256,2,2,true><<<dim3(4,256), 512, 0, stream>>>(QKVG, DbF, node_mask, Ob);
  gemm_v2<<<g256, 256, 0, stream>>>(Ob, Wro, N1, 256, 256, 7, row_out_bias, node);

  // --- column attention (in [r,s,d] layout) ---
  ln256_kernel<<<8192, 256, 0, stream>>>(N1, A, col_ln_g, col_ln_b, 1, 1);
  gemm_v2<<<g1024, 256, 0, stream>>>(A, Wcqkvg, QKVG, 1024, 256, 6, col_bg, nullptr);
  attn_mfma<128,4,2,false><<<dim3(2,512), 512, 0, stream>>>(QKVG, nullptr, node_mask, Ob);
  gemm_v2<<<g256, 256, 0, stream>>>(Ob, Wco, N2, 256, 256, 8, col_bo, (const float*)N1);

  // --- transition ---
  ln256_kernel<<<8192, 256, 0, stream>>>(N2, A, tr_ln_g, tr_ln_b, 0, 1);
  gemm_v2<<<g1024, 256, 0, stream>>>(A, W1w, T1, 1024, 256, 3, tr_b1, nullptr);
  gemm_v2<<<g256, 256, 0, stream>>>(T1, W2w, out, 256, 1024, 9, tr_b2, (const float*)N2);
}